// Round 13
// baseline (1205.824 us; speedup 1.0000x reference)
//
#include <hip/hip_runtime.h>
#include <hip/hip_bf16.h>

using bf16x8 = __attribute__((ext_vector_type(8))) short;
using f32x4  = __attribute__((ext_vector_type(4))) float;
using u16x4  = __attribute__((ext_vector_type(4))) unsigned short;

#define DEVI static __device__ __forceinline__

DEVI unsigned short f2b(float f) {           // f32 -> bf16 RNE
  unsigned int u = __float_as_uint(f);
  u += 0x7FFFu + ((u >> 16) & 1u);
  return (unsigned short)(u >> 16);
}

DEVI void gload16(const unsigned short* g, unsigned short* l) {
  __builtin_amdgcn_global_load_lds(
      (const __attribute__((address_space(1))) unsigned int*)g,
      (__attribute__((address_space(3))) unsigned int*)l, 16, 0, 0);
}

DEVI float wred_max16(float v) {
#pragma unroll
  for (int m = 1; m < 16; m <<= 1) v = fmaxf(v, __shfl_xor(v, m, 64));
  return v;
}
DEVI float wred_sum16(float v) {
#pragma unroll
  for (int m = 1; m < 16; m <<= 1) v += __shfl_xor(v, m, 64);
  return v;
}

// ---------------- elementwise / pack kernels ----------------

__global__ void cvt_kernel(const float* __restrict__ in,
                           unsigned short* __restrict__ out, int n4) {
  int i = blockIdx.x * blockDim.x + threadIdx.x;
  const int stride = gridDim.x * blockDim.x;
  for (; i < n4; i += stride) {
    const float4 v = ((const float4*)in)[i];
    u16x4 o;
    o[0] = f2b(v.x); o[1] = f2b(v.y); o[2] = f2b(v.z); o[3] = f2b(v.w);
    ((u16x4*)out)[i] = o;
  }
}

// Pack rows of up to 3 source weight tensors ([L][2][1024][1024] f32, sub-slot
// `sub`) into a fused bf16 buffer dst[l][nm*1024][1024].
__global__ void pack_w(const float* __restrict__ s0,
                       const float* __restrict__ s1,
                       const float* __restrict__ s2,
                       int sub, unsigned short* __restrict__ dst, int nm) {
  const int r = blockIdx.x;      // row 0..1023
  const int m = blockIdx.y;      // matrix slot
  const int l = blockIdx.z;      // layer
  const float* src = (m == 0 ? s0 : m == 1 ? s1 : s2)
                   + (size_t)(l * 2 + sub) * 1048576 + (size_t)r * 1024;
  unsigned short* d = dst + ((size_t)(l * nm + m) * 1024 + r) * 1024;
  const int col = threadIdx.x * 4;
  const float4 v = *(const float4*)(src + col);
  u16x4 o;
  o[0] = f2b(v.x); o[1] = f2b(v.y); o[2] = f2b(v.z); o[3] = f2b(v.w);
  *(u16x4*)(d + col) = o;
}

__global__ void pack_bias(const float* __restrict__ s0,
                          const float* __restrict__ s1,
                          const float* __restrict__ s2,
                          int sub, float* __restrict__ dst, int nm) {
  const int m = blockIdx.x, l = blockIdx.y;
  const float* src = (m == 0 ? s0 : m == 1 ? s1 : s2) + (size_t)(l * 2 + sub) * 1024;
  float* d = dst + ((size_t)l * nm + m) * 1024;
  const int i = threadIdx.x * 4;
  *(float4*)(d + i) = *(const float4*)(src + i);
}

__global__ void embed_kernel(const int* __restrict__ ids,
                             const float* __restrict__ emb,
                             const float* __restrict__ pe,
                             float* __restrict__ x) {
  const int row = blockIdx.x;           // b*512 + t
  const int t = row & 511;
  const int col = threadIdx.x * 4;      // 256 threads
  const int id = ids[row];
  const float4 e = *(const float4*)(emb + (size_t)id * 1024 + col);
  const float4 p = *(const float4*)(pe + (size_t)t * 1024 + col);
  float4 o;
  o.x = e.x * 32.f + p.x; o.y = e.y * 32.f + p.y;
  o.z = e.z * 32.f + p.z; o.w = e.w * 32.f + p.w;
  *(float4*)(x + (size_t)row * 1024 + col) = o;
}

__global__ void ln_kernel(const float* __restrict__ x,
                          const float* __restrict__ g,
                          const float* __restrict__ b,
                          unsigned short* __restrict__ out) {
  const int row = blockIdx.x;
  const int l = threadIdx.x;            // 64 lanes, 16 elems each
  const float4* xr = (const float4*)(x + (size_t)row * 1024);
  float4 v[4];
  float s = 0.f;
#pragma unroll
  for (int i = 0; i < 4; ++i) {
    v[i] = xr[l * 4 + i];
    s += v[i].x + v[i].y + v[i].z + v[i].w;
  }
#pragma unroll
  for (int m = 1; m < 64; m <<= 1) s += __shfl_xor(s, m, 64);
  const float mean = s * (1.f / 1024.f);
  float vs = 0.f;
#pragma unroll
  for (int i = 0; i < 4; ++i) {
    float dx = v[i].x - mean, dy = v[i].y - mean, dz = v[i].z - mean, dw = v[i].w - mean;
    vs += dx * dx + dy * dy + dz * dz + dw * dw;
  }
#pragma unroll
  for (int m = 1; m < 64; m <<= 1) vs += __shfl_xor(vs, m, 64);
  const float inv = rsqrtf(vs * (1.f / 1024.f) + 1e-5f);
#pragma unroll
  for (int i = 0; i < 4; ++i) {
    const int col = l * 16 + i * 4;
    const float4 gg = *(const float4*)(g + col);
    const float4 bb = *(const float4*)(b + col);
    u16x4 o;
    o[0] = f2b((v[i].x - mean) * inv * gg.x + bb.x);
    o[1] = f2b((v[i].y - mean) * inv * gg.y + bb.y);
    o[2] = f2b((v[i].z - mean) * inv * gg.z + bb.z);
    o[3] = f2b((v[i].w - mean) * inv * gg.w + bb.w);
    *(u16x4*)(out + (size_t)row * 1024 + col) = o;
  }
}

// Transpose per-head V into Vt[b][h][d=64][t=512] for vectorized PV loads.
__global__ void vt_kernel(const unsigned short* __restrict__ Vsrc, int vsd,
                          unsigned short* __restrict__ Vt) {
  __shared__ alignas(16) unsigned short t[64][72];
  const int tt = blockIdx.x;     // token tile 0..7
  const int h  = blockIdx.y;
  const int b  = blockIdx.z;
  const int tid = threadIdx.x;
  const int r  = tid >> 2;       // token in tile (0..63)
  const int ch = tid & 3;        // 16-elem d chunk (0..3)
  const unsigned short* src =
      Vsrc + (size_t)(b * 512 + tt * 64 + r) * vsd + (size_t)h * 64 + ch * 16;
  const bf16x8 v0 = *(const bf16x8*)src;
  const bf16x8 v1 = *(const bf16x8*)(src + 8);
#pragma unroll
  for (int j = 0; j < 8; ++j) {
    t[ch * 16 + j][r]     = (unsigned short)v0[j];
    t[ch * 16 + 8 + j][r] = (unsigned short)v1[j];
  }
  __syncthreads();
  const int d  = tid >> 2;       // d (0..63)
  const int tp = tid & 3;        // token sub-chunk (16 tokens)
  unsigned short* dst = Vt + (((size_t)(b * 16 + h) * 64 + d) * 512) + tt * 64 + tp * 16;
  *(bf16x8*)dst       = *(const bf16x8*)&t[d][tp * 16];
  *(bf16x8*)(dst + 8) = *(const bf16x8*)&t[d][tp * 16 + 8];
}

// ------------- fat GEMM: 256x128 tile, 8 waves, 3-slot LDS ring -------------

template<int EPI>  // 0 = bf16, 1 = relu+bf16
__global__ __launch_bounds__(512, 2) void gemm256(
    const unsigned short* __restrict__ A,
    const unsigned short* __restrict__ Bw,
    const float* __restrict__ bias,
    int N, unsigned short* __restrict__ out0) {
  constexpr int K = 1024, NK = 16;
  __shared__ alignas(16) unsigned short As0[256 * 64];
  __shared__ alignas(16) unsigned short As1[256 * 64];
  __shared__ alignas(16) unsigned short As2[256 * 64];
  __shared__ alignas(16) unsigned short Bs0[128 * 64];
  __shared__ alignas(16) unsigned short Bs1[128 * 64];
  __shared__ alignas(16) unsigned short Bs2[128 * 64];
  const int tid = threadIdx.x;
  const int lane = tid & 63;
  const int wave = tid >> 6;
  const int wr = wave >> 2;
  const int wc = wave & 3;
  int id = blockIdx.x;
  const int nwg = gridDim.x;
  id = (id & 7) * (nwg >> 3) + (id >> 3);
  const int nn = N >> 7;
  const int bx = id % nn;
  const int by = id / nn;
  const int m0 = by * 256;
  const int n0 = bx * 128;
  const int ro = lane & 15;
  const int hi = lane >> 4;

  auto stageA = [&](unsigned short* dst, int kt) {
    const size_t k0 = (size_t)kt * 64;
#pragma unroll
    for (int i = 0; i < 4; ++i) {
      const int c = tid + 512 * i;
      const int row = c >> 3;
      const int lc = (c & 7) ^ (row & 7);
      gload16(A + (size_t)(m0 + row) * K + k0 + lc * 8, dst + c * 8);
    }
  };
  auto stageB = [&](unsigned short* dst, int kt) {
    const size_t k0 = (size_t)kt * 64;
#pragma unroll
    for (int i = 0; i < 2; ++i) {
      const int c = tid + 512 * i;
      const int row = c >> 3;
      const int lc = (c & 7) ^ (row & 7);
      gload16(Bw + (size_t)(n0 + row) * K + k0 + lc * 8, dst + c * 8);
    }
  };

  f32x4 acc[8][2];
#pragma unroll
  for (int i = 0; i < 8; ++i)
#pragma unroll
    for (int j = 0; j < 2; ++j) acc[i][j] = f32x4{0.f, 0.f, 0.f, 0.f};

  stageA(As0, 0); stageB(Bs0, 0);
  stageA(As1, 1); stageB(Bs1, 1);

  auto body = [&](int kt, const unsigned short* Ac, const unsigned short* Bc,
                  unsigned short* An, unsigned short* Bn, bool last) {
    if (last) asm volatile("s_waitcnt vmcnt(0)" ::: "memory");
    else      asm volatile("s_waitcnt vmcnt(6)" ::: "memory");
    __builtin_amdgcn_s_barrier();
    if (kt + 2 < NK) { stageA(An, kt + 2); stageB(Bn, kt + 2); }
    bf16x8 af[8][2], bf[2][2];
#pragma unroll
    for (int mi = 0; mi < 8; ++mi) {
      const int r = wr * 128 + mi * 16 + ro;
#pragma unroll
      for (int ks = 0; ks < 2; ++ks)
        af[mi][ks] = *(const bf16x8*)&Ac[r * 64 + (((ks << 2) + hi) ^ (r & 7)) * 8];
    }
#pragma unroll
    for (int nj = 0; nj < 2; ++nj) {
      const int r = wc * 32 + nj * 16 + ro;
#pragma unroll
      for (int ks = 0; ks < 2; ++ks)
        bf[nj][ks] = *(const bf16x8*)&Bc[r * 64 + (((ks << 2) + hi) ^ (r & 7)) * 8];
    }
    __builtin_amdgcn_s_setprio(1);
#pragma unroll
    for (int ks = 0; ks < 2; ++ks)
#pragma unroll
      for (int mi = 0; mi < 8; ++mi)
#pragma unroll
        for (int nj = 0; nj < 2; ++nj)
          acc[mi][nj] = __builtin_amdgcn_mfma_f32_16x16x32_bf16(af[mi][ks], bf[nj][ks], acc[mi][nj], 0, 0, 0);
    __builtin_amdgcn_s_setprio(0);
  };

  for (int base = 0; base < 15; base += 3) {
    body(base,     As0, Bs0, As2, Bs2, false);
    body(base + 1, As1, Bs1, As0, Bs0, false);
    body(base + 2, As2, Bs2, As1, Bs1, false);
  }
  body(15, As0, Bs0, As1, Bs1, true);

  const int r4 = hi * 4;
#pragma unroll
  for (int mi = 0; mi < 8; ++mi) {
#pragma unroll
    for (int nj = 0; nj < 2; ++nj) {
      const int cg = n0 + wc * 32 + nj * 16 + ro;
      const float bv = bias[cg];
#pragma unroll
      for (int q = 0; q < 4; ++q) {
        const int rg = m0 + wr * 128 + mi * 16 + r4 + q;
        const float v = acc[mi][nj][q] + bv;
        out0[(size_t)rg * N + cg] = f2b(EPI == 1 ? fmaxf(v, 0.f) : v);
      }
    }
  }
}

// ---------------- skinny GEMM (R7 structure, BM=128, BN=64) ----------------

enum { EPI_BF16 = 0, EPI_RELU_BF16 = 1, EPI_RES = 2, EPI_RES2 = 3 };

template<int EPI, int BM, int BN>
__global__ void gemm_bt(const unsigned short* __restrict__ A,
                        const unsigned short* __restrict__ Bw,
                        const float* __restrict__ bias,
                        int N, int K, int nn,
                        void* out0, const float* res, float* out1) {
  constexpr int MI = BM / 32;
  constexpr int NJ = BN / 32;
  __shared__ alignas(16) unsigned short As[2][BM * 64];
  __shared__ alignas(16) unsigned short Bs[2][BN * 64];
  const int tid = threadIdx.x;
  const int lane = tid & 63;
  const int wave = tid >> 6;
  int id = blockIdx.x;
  const int nwg = gridDim.x;
  id = (id & 7) * (nwg >> 3) + (id >> 3);
  const int bx = id % nn;
  const int by = id / nn;
  const int m0 = by * BM;
  const int n0 = bx * BN;
  const int wm = (wave >> 1) * (BM / 2);
  const int wn = (wave & 1) * (BN / 2);

  auto stage = [&](int buf, int kt) {
    const size_t k0 = (size_t)kt * 64;
#pragma unroll
    for (int i = 0; i < MI; ++i) {
      const int c = tid + 256 * i;
      const int row = c >> 3;
      const int lc = (c & 7) ^ (row & 7);
      gload16(A + (size_t)(m0 + row) * K + k0 + lc * 8, &As[buf][c * 8]);
    }
#pragma unroll
    for (int i = 0; i < NJ; ++i) {
      const int c = tid + 256 * i;
      const int row = c >> 3;
      const int lc = (c & 7) ^ (row & 7);
      gload16(Bw + (size_t)(n0 + row) * K + k0 + lc * 8, &Bs[buf][c * 8]);
    }
  };

  f32x4 acc[MI][NJ];
#pragma unroll
  for (int i = 0; i < MI; ++i)
#pragma unroll
    for (int j = 0; j < NJ; ++j) acc[i][j] = f32x4{0.f, 0.f, 0.f, 0.f};

  const int nk = K >> 6;
  stage(0, 0);
  int cur = 0;
  const int ro = lane & 15;
  const int hi = lane >> 4;
  for (int kt = 0; kt < nk; ++kt) {
    __syncthreads();
    if (kt + 1 < nk) stage(cur ^ 1, kt + 1);
    bf16x8 af[MI][2], bf[NJ][2];
#pragma unroll
    for (int i = 0; i < MI; ++i) {
      const int r = wm + i * 16 + ro;
#pragma unroll
      for (int ks = 0; ks < 2; ++ks)
        af[i][ks] = *(const bf16x8*)&As[cur][r * 64 + (((ks << 2) + hi) ^ (r & 7)) * 8];
    }
#pragma unroll
    for (int j = 0; j < NJ; ++j) {
      const int r = wn + j * 16 + ro;
#pragma unroll
      for (int ks = 0; ks < 2; ++ks)
        bf[j][ks] = *(const bf16x8*)&Bs[cur][r * 64 + (((ks << 2) + hi) ^ (r & 7)) * 8];
    }
#pragma unroll
    for (int ks = 0; ks < 2; ++ks)
#pragma unroll
      for (int i = 0; i < MI; ++i)
#pragma unroll
        for (int j = 0; j < NJ; ++j)
          acc[i][j] = __builtin_amdgcn_mfma_f32_16x16x32_bf16(af[i][ks], bf[j][ks], acc[i][j], 0, 0, 0);
    cur ^= 1;
  }

  const int r4 = hi * 4;
#pragma unroll
  for (int i = 0; i < MI; ++i) {
#pragma unroll
    for (int j = 0; j < NJ; ++j) {
      const int cg = n0 + wn + j * 16 + ro;
      const float bv = bias[cg];
#pragma unroll
      for (int q = 0; q < 4; ++q) {
        const int rg = m0 + wm + i * 16 + r4 + q;
        const size_t idx = (size_t)rg * N + cg;
        const float v = acc[i][j][q] + bv;
        if (EPI == EPI_BF16) {
          ((unsigned short*)out0)[idx] = f2b(v);
        } else if (EPI == EPI_RELU_BF16) {
          ((unsigned short*)out0)[idx] = f2b(fmaxf(v, 0.f));
        } else if (EPI == EPI_RES) {
          ((float*)out0)[idx] = res[idx] + v;
        } else {
          const float r = res[idx];
          ((float*)out0)[idx] = v;
          out1[idx] = r + v;
        }
      }
    }
  }
}

// ------------- FFN2 split-K GEMM: partials, single 1024-block launch -------------
// A = mid [4096][4096], Bw = W2 [1024][4096]; split s owns K-range
// [s*2048, (s+1)*2048). Writes f32 partial p[s][4096][1024] (no bias).

__global__ void gemm_sk(const unsigned short* __restrict__ A,
                        const unsigned short* __restrict__ Bw,
                        float* __restrict__ pbuf) {
  constexpr int BM = 128, BN = 64, MI = 4, NJ = 2, LDA = 4096;
  __shared__ alignas(16) unsigned short As[2][BM * 64];
  __shared__ alignas(16) unsigned short Bs[2][BN * 64];
  const int tid = threadIdx.x;
  const int lane = tid & 63;
  const int wave = tid >> 6;
  int id = blockIdx.x;
  const int nwg = gridDim.x;              // 1024
  id = (id & 7) * (nwg >> 3) + (id >> 3); // XCD swizzle
  const int s  = id >> 9;                 // split 0/1
  const int r9 = id & 511;
  const int bx = r9 & 15;                 // 16 col tiles
  const int by = r9 >> 4;                 // 32 row tiles
  const int m0 = by * BM;
  const int n0 = bx * BN;
  const int kofs = s * 2048;
  const int wm = (wave >> 1) * 64;
  const int wn = (wave & 1) * 32;

  auto stage = [&](int buf, int kt) {
    const size_t k0 = (size_t)(kofs + kt * 64);
#pragma unroll
    for (int i = 0; i < MI; ++i) {
      const int c = tid + 256 * i;
      const int row = c >> 3;
      const int lc = (c & 7) ^ (row & 7);
      gload16(A + (size_t)(m0 + row) * LDA + k0 + lc * 8, &As[buf][c * 8]);
    }
#pragma unroll
    for (int i = 0; i < NJ; ++i) {
      const int c = tid + 256 * i;
      const int row = c >> 3;
      const int lc = (c & 7) ^ (row & 7);
      gload16(Bw + (size_t)(n0 + row) * LDA + k0 + lc * 8, &Bs[buf][c * 8]);
    }
  };

  f32x4 acc[MI][NJ];
#pragma unroll
  for (int i = 0; i < MI; ++i)
#pragma unroll
    for (int j = 0; j < NJ; ++j) acc[i][j] = f32x4{0.f, 0.f, 0.f, 0.f};

  const int nk = 32;                      // 2048 / 64
  stage(0, 0);
  int cur = 0;
  const int ro = lane & 15;
  const int hi = lane >> 4;
  for (int kt = 0; kt < nk; ++kt) {
    __syncthreads();
    if (kt + 1 < nk) stage(cur ^ 1, kt + 1);
    bf16x8 af[MI][2], bf[NJ][2];
#pragma unroll
    for (int i = 0; i < MI; ++i) {
      const int r = wm + i * 16 + ro;
#pragma unroll
      for (int ks = 0; ks < 2; ++ks)
        af[i][ks] = *(const bf16x8*)&As[cur][r * 64 + (((ks << 2) + hi) ^ (r & 7)) * 8];
    }
#pragma unroll
    for (int j = 0; j < NJ; ++j) {
      const int r = wn + j * 16 + ro;
#pragma unroll
      for (int ks = 0; ks < 2; ++ks)
        bf[j][ks] = *(const bf16x8*)&Bs[cur][r * 64 + (((ks << 2) + hi) ^ (r & 7)) * 8];
    }
#pragma unroll
    for (int ks = 0; ks < 2; ++ks)
#pragma unroll
      for (int i = 0; i < MI; ++i)
#pragma unroll
        for (int j = 0; j < NJ; ++j)
          acc[i][j] = __builtin_amdgcn_mfma_f32_16x16x32_bf16(af[i][ks], bf[j][ks], acc[i][j], 0, 0, 0);
    cur ^= 1;
  }

  float* out = pbuf + (size_t)s * 4096 * 1024;
  const int r4 = hi * 4;
#pragma unroll
  for (int i = 0; i < MI; ++i)
#pragma unroll
    for (int j = 0; j < NJ; ++j) {
      const int cg = n0 + wn + j * 16 + ro;
#pragma unroll
      for (int q = 0; q < 4; ++q) {
        const int rg = m0 + wm + i * 16 + r4 + q;
        out[(size_t)rg * 1024 + cg] = acc[i][j][q];
      }
    }
}

// xout = c + p0 + p1 + bias   (f32, vectorized)
__global__ void reduce2_kernel(const float* __restrict__ c,
                               const float* __restrict__ pbuf,
                               const float* __restrict__ bias,
                               float* __restrict__ xout) {
  const int n4 = 4096 * 1024 / 4;
  int i = blockIdx.x * blockDim.x + threadIdx.x;
  const int stride = gridDim.x * blockDim.x;
  const float4* p0 = (const float4*)pbuf;
  const float4* p1 = (const float4*)(pbuf + 4096 * 1024);
  for (; i < n4; i += stride) {
    const float4 cc = ((const float4*)c)[i];
    const float4 a0 = p0[i];
    const float4 a1 = p1[i];
    const float4 bb = ((const float4*)bias)[i & 255];
    float4 o;
    o.x = cc.x + a0.x + a1.x + bb.x;
    o.y = cc.y + a0.y + a1.y + bb.y;
    o.z = cc.z + a0.z + a1.z + bb.z;
    o.w = cc.w + a0.w + a1.w + bb.w;
    ((float4*)xout)[i] = o;
  }
}

// ---------------- fused flash attention (4-wave, LDS-staged K/V) ----------------

template<bool CAUSAL>
__global__ __launch_bounds__(256) void attn_kernel(
    const unsigned short* __restrict__ Qg, int qs,
    const unsigned short* __restrict__ Kg, int ksd,
    const unsigned short* __restrict__ Vt,
    unsigned short* __restrict__ Og) {
  __shared__ alignas(16) unsigned short Ks[2][64 * 64];
  __shared__ alignas(16) unsigned short Vs[2][64 * 64];
  __shared__ alignas(16) unsigned short Pl[4][32 * 64];
  const int qt0 = blockIdx.x;
  const int h  = blockIdx.y;
  const int b  = blockIdx.z;
  const int tid = threadIdx.x;
  const int lane = tid & 63;
  const int w = tid >> 6;
  const int ro = lane & 15;
  const int hi = lane >> 4;
  const int qrow0 = qt0 * 128 + w * 32;
  const size_t qbase = (size_t)b * 512 * qs  + (size_t)h * 64;
  const size_t kbase = (size_t)b * 512 * ksd + (size_t)h * 64;
  const size_t vbase = ((size_t)(b * 16 + h)) * 64 * 512;
  const size_t obase = (size_t)b * 512 * 1024 + (size_t)h * 64;

  bf16x8 qf[2][2];
#pragma unroll
  for (int mi = 0; mi < 2; ++mi)
#pragma unroll
    for (int ks = 0; ks < 2; ++ks)
      qf[mi][ks] = *(const bf16x8*)&Qg[qbase + (size_t)(qrow0 + mi * 16 + ro) * qs + ks * 32 + hi * 8];

  f32x4 o[2][4];
  float mrun[2][4], lrun[2][4];
#pragma unroll
  for (int mi = 0; mi < 2; ++mi) {
#pragma unroll
    for (int di = 0; di < 4; ++di) o[mi][di] = f32x4{0.f, 0.f, 0.f, 0.f};
#pragma unroll
    for (int q = 0; q < 4; ++q) { mrun[mi][q] = -1e30f; lrun[mi][q] = 0.f; }
  }

  auto stage = [&](int buf, int kt) {
#pragma unroll
    for (int i = 0; i < 2; ++i) {
      const int c = tid + 256 * i;
      const int row = c >> 3;
      const int lc = (c & 7) ^ (row & 7);
      gload16(Kg + kbase + (size_t)(kt * 64 + row) * ksd + lc * 8, &Ks[buf][c * 8]);
    }
#pragma unroll
    for (int i = 0; i < 2; ++i) {
      const int c = tid + 256 * i;
      const int row = c >> 3;
      const int lc = (c & 7) ^ (row & 7);
      gload16(Vt + vbase + (size_t)row * 512 + (size_t)kt * 64 + lc * 8, &Vs[buf][c * 8]);
    }
  };

  const int ktmax = CAUSAL ? (qt0 * 2 + 1) : 7;
  stage(0, 0);
  int cur = 0;
  for (int kt = 0; kt <= ktmax; ++kt) {
    __syncthreads();
    if (kt < ktmax) stage(cur ^ 1, kt + 1);
    const bool skip = CAUSAL && (kt * 64 > qrow0 + 31);
    if (!skip) {
      bf16x8 kf[4][2];
#pragma unroll
      for (int ni = 0; ni < 4; ++ni) {
        const int r = ni * 16 + ro;
#pragma unroll
        for (int ks = 0; ks < 2; ++ks)
          kf[ni][ks] = *(const bf16x8*)&Ks[cur][r * 64 + (((ks << 2) + hi) ^ (r & 7)) * 8];
      }

      f32x4 s[2][4];
#pragma unroll
      for (int mi = 0; mi < 2; ++mi)
#pragma unroll
        for (int ni = 0; ni < 4; ++ni) s[mi][ni] = f32x4{0.f, 0.f, 0.f, 0.f};
#pragma unroll
      for (int ks = 0; ks < 2; ++ks)
#pragma unroll
        for (int mi = 0; mi < 2; ++mi)
#pragma unroll
          for (int ni = 0; ni < 4; ++ni)
            s[mi][ni] = __builtin_amdgcn_mfma_f32_16x16x32_bf16(qf[mi][ks], kf[ni][ks], s[mi][ni], 0, 0, 0);

      const bool dm = CAUSAL && (kt * 64 + 63 > qrow0);
#pragma unroll
      for (int mi = 0; mi < 2; ++mi)
#pragma unroll
        for (int ni = 0; ni < 4; ++ni)
#pragma unroll
          for (int q = 0; q < 4; ++q) {
            float e = s[mi][ni][q] * 0.125f;
            if (dm && (kt * 64 + ni * 16 + ro) > (qrow0 + mi * 16 + hi * 4 + q)) e = -1e9f;
            s[mi][ni][q] = e;
          }

      float fac[2][4];
#pragma unroll
      for (int mi = 0; mi < 2; ++mi)
#pragma unroll
        for (int q = 0; q < 4; ++q) {
          float rm = s[mi][0][q];
#pragma unroll
          for (int ni = 1; ni < 4; ++ni) rm = fmaxf(rm, s[mi][ni][q]);
          rm = wred_max16(rm);
          const float mn = fmaxf(mrun[mi][q], rm);
          fac[mi][q] = __expf(mrun[mi][q] - mn);
          mrun[mi][q] = mn;
        }
#pragma unroll
      for (int mi = 0; mi < 2; ++mi)
#pragma unroll
        for (int q = 0; q < 4; ++q) {
          float rs = 0.f;
#pragma unroll
          for (int ni = 0; ni < 4; ++ni) {
            const float pv = __expf(s[mi][ni][q] - mrun[mi][q]);
            s[mi][ni][q] = pv;
            rs += pv;
          }
          rs = wred_sum16(rs);
          lrun[mi][q] = lrun[mi][q] * fac[mi][q] + rs;
        }
#pragma unroll
      for (int mi = 0; mi < 2; ++mi)
#pragma unroll
        for (int di = 0; di < 4; ++di)
#pragma unroll
          for (int q = 0; q < 4; ++q) o[mi][di][q] *= fac[mi][q];

#pragma unroll
      for (int mi = 0; mi < 2; ++mi)
#pragma unroll
        for (int ni = 0; ni < 4; ++ni)
#pragma unroll
          for (int q = 0; q < 4; ++q) {
            const int row = mi * 16 + hi * 4 + q;
            const int col = ni * 16 + ro;
            const int sc  = ((col >> 3) ^ (row & 7)) * 8 + (col & 7);
            Pl[w][row * 64 + sc] = f2b(s[mi][ni][q]);
          }

      bf16x8 pa[2][2];
#pragma unroll
      for (int mi = 0; mi < 2; ++mi)
#pragma unroll
        for (int ks = 0; ks < 2; ++ks) {
          const int row = mi * 16 + ro;
          pa[mi][ks] = *(const bf16x8*)&Pl[w][row * 64 + (((ks << 2) + hi) ^ (row & 7)) * 8];
        }

#pragma unroll
      for (int di = 0; di < 4; ++di)
#pragma unroll
        for (int ks = 0; ks < 2; ++ks) {
          const int r = di * 16 + ro;
          const bf16x8 vf = *(const bf16x8*)&Vs[cur][r * 64 + (((ks << 2) + hi) ^ (r & 7)) * 8];
#pragma unroll
          for (int mi = 0; mi < 2; ++mi)
            o[mi][di] = __builtin_amdgcn_mfma_f32_16x16x32_bf16(pa[mi][ks], vf, o[mi][di], 0, 0, 0);
        }
    }
    cur ^= 1;
  }

#pragma unroll
  for (int mi = 0; mi < 2; ++mi)
#pragma unroll
    for (int di = 0; di < 4; ++di)
#pragma unroll
      for (int q = 0; q < 4; ++q) {
        const float val = o[mi][di][q] / lrun[mi][q];
        Og[obase + (size_t)(qrow0 + mi * 16 + hi * 4 + q) * 1024 + di * 16 + ro] = f2b(val);
      }
}

// ---------------- host orchestration ----------------

extern "C" void kernel_launch(void* const* d_in, const int* in_sizes, int n_in,
                              void* d_out, int out_size, void* d_ws, size_t ws_size,
                              hipStream_t stream) {
  (void)in_sizes; (void)n_in; (void)out_size; (void)ws_size;
  const int*   dec = (const int*)d_in[0];
  const float* enc = (const float*)d_in[2];
  const float* emb = (const float*)d_in[4];
  const float* pe  = (const float*)d_in[5];
  const float* wq  = (const float*)d_in[6];
  const float* bq  = (const float*)d_in[7];
  const float* wk  = (const float*)d_in[8];
  const float* bk  = (const float*)d_in[9];
  const float* wv  = (const float*)d_in[10];
  const float* bv  = (const float*)d_in[11];
  const float* wo  = (const float*)d_in[12];
  const float* bo  = (const float*)d_in[13];
  const float* w1  = (const float*)d_in[14];
  const float* b1  = (const float*)d_in[15];
  const float* w2  = (const float*)d_in[16];
  const float* b2  = (const float*)d_in[17];
  const float* lng = (const float*)d_in[18];
  const float* lnb = (const float*)d_in[19];

  const size_t SZ_ACT = 4194304ull;     // 4096*1024

  char* p = (char*)d_ws;
  auto alloc = [&](size_t bytes) { char* r = p; p += (bytes + 255) & ~(size_t)255; return r; };
  unsigned short* qkvw  = (unsigned short*)alloc(3ull * 3 * 1048576 * 2);  // [L][3072][1024]
  unsigned short* kvw   = (unsigned short*)alloc(3ull * 2 * 1048576 * 2);  // [6144][1024]
  unsigned short* wqxb  = (unsigned short*)alloc(3ull * 1048576 * 2);      // [L][1024][1024]
  unsigned short* Wob   = (unsigned short*)alloc(6291456ull * 2);          // [L][2][1024][1024]
  unsigned short* W1b   = (unsigned short*)alloc(12582912ull * 2);
  unsigned short* W2b   = (unsigned short*)alloc(12582912ull * 2);
  unsigned short* encb  = (unsigned short*)alloc(SZ_ACT * 2);
  float*          x     = (float*)alloc(SZ_ACT * 4);
  float*          c     = (float*)alloc(SZ_ACT * 4);
  unsigned short* hb    = (unsigned short*)alloc(SZ_ACT * 2);
  unsigned short* qkvb  = (unsigned short*)alloc(4096ull * 3072 * 2);
  unsigned short* kvb   = (unsigned short*)alloc(4096ull * 6144 * 2);      // merged 3-layer K/V
  unsigned short* qb    = (unsigned short*)alloc(SZ_ACT * 2);
  unsigned short* vtb   = (unsigned short*)alloc(SZ_ACT * 2);              // [B][H][64][512]
  unsigned short* mid   = (unsigned short*)alloc(4096ull * 4096 * 2);
  float*          pbuf  = (float*)alloc(2ull * SZ_ACT * 4);                // split-K partials
  float*          qkvbias = (float*)alloc(3ull * 3072 * 4);
  float*          kvbias  = (float*)alloc(3ull * 2048 * 4);

  cvt_kernel<<<2048, 256, 0, stream>>>(wo, Wob, 1572864);
  cvt_kernel<<<2048, 256, 0, stream>>>(w1, W1b, 3145728);
  cvt_kernel<<<2048, 256, 0, stream>>>(w2, W2b, 3145728);
  cvt_kernel<<<2048, 256, 0, stream>>>(enc, encb, 1048576);
  pack_w<<<dim3(1024, 3, 3), 256, 0, stream>>>(wq, wk, wv, 0, qkvw, 3);
  pack_w<<<dim3(1024, 2, 3), 256, 0, stream>>>(wk, wv, wv, 1, kvw, 2);
  pack_w<<<dim3(1024, 1, 3), 256, 0, stream>>>(wq, wq, wq, 1, wqxb, 1);
  pack_bias<<<dim3(3, 3), 256, 0, stream>>>(bq, bk, bv, 0, qkvbias, 3);
  pack_bias<<<dim3(2, 3), 256, 0, stream>>>(bk, bv, bv, 1, kvbias, 2);
  embed_kernel<<<4096, 256, 0, stream>>>(dec, emb, pe, x);

  // merged cross-attn K/V for all 3 layers: [4096][6144]
  gemm256<0><<<48 * 16, 512, 0, stream>>>(encb, kvw, kvbias, 6144, kvb);

  const dim3 gAttn(4, 16, 8);
  const dim3 gVt(8, 16, 8);

  for (int l = 0; l < 3; ++l) {
    const float* g0 = lng + (l * 3 + 0) * 1024; const float* e0 = lnb + (l * 3 + 0) * 1024;
    const float* g1 = lng + (l * 3 + 1) * 1024; const float* e1 = lnb + (l * 3 + 1) * 1024;
    const float* g2 = lng + (l * 3 + 2) * 1024; const float* e2 = lnb + (l * 3 + 2) * 1024;

    // ---- self-attention sublayer ----
    ln_kernel<<<4096, 64, 0, stream>>>(x, g0, e0, hb);
    gemm256<0><<<24 * 16, 512, 0, stream>>>(hb, qkvw + (size_t)l * 3 * 1048576,
        qkvbias + l * 3072, 3072, qkvb);
    vt_kernel<<<gVt, 256, 0, stream>>>(qkvb + 2048, 3072, vtb);
    attn_kernel<true><<<gAttn, 256, 0, stream>>>(qkvb, 3072, qkvb + 1024, 3072, vtb, hb);
    gemm_bt<EPI_RES, 128, 64><<<32 * 16, 256, 0, stream>>>(hb, Wob + (size_t)(l * 2) * 1048576,
        bo + (l * 2) * 1024, 1024, 1024, 16, x, x, nullptr);

    // ---- cross-attention sublayer ----
    ln_kernel<<<4096, 64, 0, stream>>>(x, g1, e1, hb);
    gemm_bt<EPI_BF16, 128, 64><<<32 * 16, 256, 0, stream>>>(hb, wqxb + (size_t)l * 1048576,
        bq + (l * 2 + 1) * 1024, 1024, 1024, 16, qb, nullptr, nullptr);
    vt_kernel<<<gVt, 256, 0, stream>>>(kvb + l * 2048 + 1024, 6144, vtb);
    attn_kernel<false><<<gAttn, 256, 0, stream>>>(qb, 1024, kvb + l * 2048, 6144, vtb, hb);
    gemm_bt<EPI_RES2, 128, 64><<<32 * 16, 256, 0, stream>>>(hb, Wob + (size_t)(l * 2 + 1) * 1048576,
        bo + (l * 2 + 1) * 1024, 1024, 1024, 16, c, x, x);

    // ---- FFN sublayer (residual is c, per reference quirk) ----
    ln_kernel<<<4096, 64, 0, stream>>>(x, g2, e2, hb);
    gemm256<1><<<32 * 16, 512, 0, stream>>>(hb, W1b + (size_t)l * 4194304,
        b1 + l * 4096, 4096, mid);
    // FFN2 via split-K=2: one 1024-block launch -> partials -> fused reduce
    gemm_sk<<<1024, 256, 0, stream>>>(mid, W2b + (size_t)l * 4194304, pbuf);
    float* xout = (l == 2) ? (float*)d_out : x;
    reduce2_kernel<<<2048, 256, 0, stream>>>(c, pbuf, b2 + l * 1024, xout);
  }
}

// Round 14
// 1112.377 us; speedup vs baseline: 1.0840x; 1.0840x over previous
//
#include <hip/hip_runtime.h>
#include <hip/hip_bf16.h>

using bf16x8 = __attribute__((ext_vector_type(8))) short;
using f32x4  = __attribute__((ext_vector_type(4))) float;
using u16x4  = __attribute__((ext_vector_type(4))) unsigned short;

#define DEVI static __device__ __forceinline__
#define SBAR() asm volatile("s_barrier" ::: "memory")

DEVI unsigned short f2b(float f) {           // f32 -> bf16 RNE
  unsigned int u = __float_as_uint(f);
  u += 0x7FFFu + ((u >> 16) & 1u);
  return (unsigned short)(u >> 16);
}

DEVI void gload16(const unsigned short* g, unsigned short* l) {
  __builtin_amdgcn_global_load_lds(
      (const __attribute__((address_space(1))) unsigned int*)g,
      (__attribute__((address_space(3))) unsigned int*)l, 16, 0, 0);
}

DEVI float wred_max16(float v) {
#pragma unroll
  for (int m = 1; m < 16; m <<= 1) v = fmaxf(v, __shfl_xor(v, m, 64));
  return v;
}
DEVI float wred_sum16(float v) {
#pragma unroll
  for (int m = 1; m < 16; m <<= 1) v += __shfl_xor(v, m, 64);
  return v;
}

// ---------------- elementwise / pack kernels ----------------

__global__ void cvt_kernel(const float* __restrict__ in,
                           unsigned short* __restrict__ out, int n4) {
  int i = blockIdx.x * blockDim.x + threadIdx.x;
  const int stride = gridDim.x * blockDim.x;
  for (; i < n4; i += stride) {
    const float4 v = ((const float4*)in)[i];
    u16x4 o;
    o[0] = f2b(v.x); o[1] = f2b(v.y); o[2] = f2b(v.z); o[3] = f2b(v.w);
    ((u16x4*)out)[i] = o;
  }
}

__global__ void pack_w(const float* __restrict__ s0,
                       const float* __restrict__ s1,
                       const float* __restrict__ s2,
                       int sub, unsigned short* __restrict__ dst, int nm) {
  const int r = blockIdx.x;
  const int m = blockIdx.y;
  const int l = blockIdx.z;
  const float* src = (m == 0 ? s0 : m == 1 ? s1 : s2)
                   + (size_t)(l * 2 + sub) * 1048576 + (size_t)r * 1024;
  unsigned short* d = dst + ((size_t)(l * nm + m) * 1024 + r) * 1024;
  const int col = threadIdx.x * 4;
  const float4 v = *(const float4*)(src + col);
  u16x4 o;
  o[0] = f2b(v.x); o[1] = f2b(v.y); o[2] = f2b(v.z); o[3] = f2b(v.w);
  *(u16x4*)(d + col) = o;
}

__global__ void pack_bias(const float* __restrict__ s0,
                          const float* __restrict__ s1,
                          const float* __restrict__ s2,
                          int sub, float* __restrict__ dst, int nm) {
  const int m = blockIdx.x, l = blockIdx.y;
  const float* src = (m == 0 ? s0 : m == 1 ? s1 : s2) + (size_t)(l * 2 + sub) * 1024;
  float* d = dst + ((size_t)l * nm + m) * 1024;
  const int i = threadIdx.x * 4;
  *(float4*)(d + i) = *(const float4*)(src + i);
}

__global__ void embed_kernel(const int* __restrict__ ids,
                             const float* __restrict__ emb,
                             const float* __restrict__ pe,
                             float* __restrict__ x) {
  const int row = blockIdx.x;
  const int t = row & 511;
  const int col = threadIdx.x * 4;
  const int id = ids[row];
  const float4 e = *(const float4*)(emb + (size_t)id * 1024 + col);
  const float4 p = *(const float4*)(pe + (size_t)t * 1024 + col);
  float4 o;
  o.x = e.x * 32.f + p.x; o.y = e.y * 32.f + p.y;
  o.z = e.z * 32.f + p.z; o.w = e.w * 32.f + p.w;
  *(float4*)(x + (size_t)row * 1024 + col) = o;
}

__global__ void ln_kernel(const float* __restrict__ x,
                          const float* __restrict__ g,
                          const float* __restrict__ b,
                          unsigned short* __restrict__ out) {
  const int row = blockIdx.x;
  const int l = threadIdx.x;
  const float4* xr = (const float4*)(x + (size_t)row * 1024);
  float4 v[4];
  float s = 0.f;
#pragma unroll
  for (int i = 0; i < 4; ++i) {
    v[i] = xr[l * 4 + i];
    s += v[i].x + v[i].y + v[i].z + v[i].w;
  }
#pragma unroll
  for (int m = 1; m < 64; m <<= 1) s += __shfl_xor(s, m, 64);
  const float mean = s * (1.f / 1024.f);
  float vs = 0.f;
#pragma unroll
  for (int i = 0; i < 4; ++i) {
    float dx = v[i].x - mean, dy = v[i].y - mean, dz = v[i].z - mean, dw = v[i].w - mean;
    vs += dx * dx + dy * dy + dz * dz + dw * dw;
  }
#pragma unroll
  for (int m = 1; m < 64; m <<= 1) vs += __shfl_xor(vs, m, 64);
  const float inv = rsqrtf(vs * (1.f / 1024.f) + 1e-5f);
#pragma unroll
  for (int i = 0; i < 4; ++i) {
    const int col = l * 16 + i * 4;
    const float4 gg = *(const float4*)(g + col);
    const float4 bb = *(const float4*)(b + col);
    u16x4 o;
    o[0] = f2b((v[i].x - mean) * inv * gg.x + bb.x);
    o[1] = f2b((v[i].y - mean) * inv * gg.y + bb.y);
    o[2] = f2b((v[i].z - mean) * inv * gg.z + bb.z);
    o[3] = f2b((v[i].w - mean) * inv * gg.w + bb.w);
    *(u16x4*)(out + (size_t)row * 1024 + col) = o;
  }
}

// Transpose per-head V into Vt[b][h][d=64][t=512] for vectorized PV loads.
__global__ void vt_kernel(const unsigned short* __restrict__ Vsrc, int vsd,
                          unsigned short* __restrict__ Vt) {
  __shared__ alignas(16) unsigned short t[64][72];
  const int tt = blockIdx.x;
  const int h  = blockIdx.y;
  const int b  = blockIdx.z;
  const int tid = threadIdx.x;
  const int r  = tid >> 2;
  const int ch = tid & 3;
  const unsigned short* src =
      Vsrc + (size_t)(b * 512 + tt * 64 + r) * vsd + (size_t)h * 64 + ch * 16;
  const bf16x8 v0 = *(const bf16x8*)src;
  const bf16x8 v1 = *(const bf16x8*)(src + 8);
#pragma unroll
  for (int j = 0; j < 8; ++j) {
    t[ch * 16 + j][r]     = (unsigned short)v0[j];
    t[ch * 16 + 8 + j][r] = (unsigned short)v1[j];
  }
  __syncthreads();
  const int d  = tid >> 2;
  const int tp = tid & 3;
  unsigned short* dst = Vt + (((size_t)(b * 16 + h) * 64 + d) * 512) + tt * 64 + tp * 16;
  *(bf16x8*)dst       = *(const bf16x8*)&t[d][tp * 16];
  *(bf16x8*)(dst + 8) = *(const bf16x8*)&t[d][tp * 16 + 8];
}

// ------------- 8-phase fat GEMM: 256x256 tile, 8 waves (m201 port) -------------
// K=1024 only. 8 waves = 2M x 4N, wave tile 128x64 (mi 0..7, nj 0..3).
// Per iteration: 2 ktiles (even->AsE/BsE, odd->AsO/BsO), 8 phases of
// {ds-read subtile, 2 quarter global_load_lds, barrier, 16 MFMA setprio,
//  barrier}; counted vmcnt(6) only at phases 4/8. Stage schedule is
// region-safe: each stage targets a quarter whose LDS reads completed a
// phase earlier; each read is covered by the preceding vmcnt(6).

template<int EPI>  // 0 = bf16, 1 = relu+bf16
__global__ __launch_bounds__(512, 1) void gemm8p(
    const unsigned short* __restrict__ A,
    const unsigned short* __restrict__ Bw,
    const float* __restrict__ bias,
    int N, unsigned short* __restrict__ out0) {
  constexpr int K = 1024, NT = 16;
  __shared__ alignas(16) unsigned short AsE[256 * 64];
  __shared__ alignas(16) unsigned short BsE[256 * 64];
  __shared__ alignas(16) unsigned short AsO[256 * 64];
  __shared__ alignas(16) unsigned short BsO[256 * 64];
  const int tid = threadIdx.x;
  const int lane = tid & 63;
  const int wave = tid >> 6;
  const int wr = wave >> 2;        // 0..1
  const int wc = wave & 3;         // 0..3
  int id = blockIdx.x;
  const int nwg = gridDim.x;
  id = (id & 7) * (nwg >> 3) + (id >> 3);   // XCD swizzle (grids % 8 == 0)
  const int nn = N >> 8;
  const int bx = id % nn;
  const int by = id / nn;
  const int m0 = by * 256;
  const int n0 = bx * 256;
  const int ro = lane & 15;
  const int hi = lane >> 4;

  // quarter stage: 64 rows x 64 K, 1 x 16B load per thread, linear LDS +
  // pre-swizzled global column (rule 21: inverse-swz source + swz read)
  auto stA = [&](unsigned short* buf, int q, int kt) {
    const int row = tid >> 3;
    const int lc = (tid & 7) ^ (row & 7);
    gload16(A + (size_t)(m0 + q * 64 + row) * K + (size_t)kt * 64 + lc * 8,
            buf + q * 4096 + tid * 8);
  };
  auto stB = [&](unsigned short* buf, int q, int kt) {
    const int row = tid >> 3;
    const int lc = (tid & 7) ^ (row & 7);
    gload16(Bw + (size_t)(n0 + q * 64 + row) * K + (size_t)kt * 64 + lc * 8,
            buf + q * 4096 + tid * 8);
  };

  f32x4 acc[8][4];
#pragma unroll
  for (int i = 0; i < 8; ++i)
#pragma unroll
    for (int j = 0; j < 4; ++j) acc[i][j] = f32x4{0.f, 0.f, 0.f, 0.f};

  bf16x8 af[4][2], bfL[2][2], bfR[2][2];

  auto ldAL = [&](const unsigned short* buf) {     // rows wr*128 + 0..63
#pragma unroll
    for (int mi = 0; mi < 4; ++mi) {
      const int r = wr * 128 + mi * 16 + ro;
#pragma unroll
      for (int ks = 0; ks < 2; ++ks)
        af[mi][ks] = *(const bf16x8*)&buf[r * 64 + (((ks << 2) + hi) ^ (r & 7)) * 8];
    }
  };
  auto ldAH = [&](const unsigned short* buf) {     // rows wr*128 + 64..127
#pragma unroll
    for (int mi = 0; mi < 4; ++mi) {
      const int r = wr * 128 + 64 + mi * 16 + ro;
#pragma unroll
      for (int ks = 0; ks < 2; ++ks)
        af[mi][ks] = *(const bf16x8*)&buf[r * 64 + (((ks << 2) + hi) ^ (r & 7)) * 8];
    }
  };
  auto ldBL = [&](const unsigned short* buf) {     // cols wc*64 + 0..31
#pragma unroll
    for (int nj = 0; nj < 2; ++nj) {
      const int r = wc * 64 + nj * 16 + ro;
#pragma unroll
      for (int ks = 0; ks < 2; ++ks)
        bfL[nj][ks] = *(const bf16x8*)&buf[r * 64 + (((ks << 2) + hi) ^ (r & 7)) * 8];
    }
  };
  auto ldBR = [&](const unsigned short* buf) {     // cols wc*64 + 32..63
#pragma unroll
    for (int nj = 0; nj < 2; ++nj) {
      const int r = wc * 64 + 32 + nj * 16 + ro;
#pragma unroll
      for (int ks = 0; ks < 2; ++ks)
        bfR[nj][ks] = *(const bf16x8*)&buf[r * 64 + (((ks << 2) + hi) ^ (r & 7)) * 8];
    }
  };
  auto mmQ = [&](bf16x8 (&bf)[2][2], int mo, int no) {
    __builtin_amdgcn_s_setprio(1);
#pragma unroll
    for (int ks = 0; ks < 2; ++ks)
#pragma unroll
      for (int mi = 0; mi < 4; ++mi)
#pragma unroll
        for (int nj = 0; nj < 2; ++nj)
          acc[mo + mi][no + nj] =
              __builtin_amdgcn_mfma_f32_16x16x32_bf16(af[mi][ks], bf[nj][ks],
                                                      acc[mo + mi][no + nj], 0, 0, 0);
    __builtin_amdgcn_s_setprio(0);
  };

  // prologue: ktile 0 complete + ktile 1 all but B-q2,q3 (staged at P1)
  stA(AsE, 0, 0); stA(AsE, 1, 0); stA(AsE, 2, 0); stA(AsE, 3, 0);
  stB(BsE, 0, 0); stB(BsE, 1, 0); stB(BsE, 2, 0); stB(BsE, 3, 0);
  stA(AsO, 0, 1); stA(AsO, 1, 1); stA(AsO, 2, 1); stA(AsO, 3, 1);
  stB(BsO, 0, 1); stB(BsO, 1, 1);
  asm volatile("s_waitcnt vmcnt(0)" ::: "memory");
  SBAR();

  for (int t = 0; t < NT; t += 2) {
    const bool last = (t + 2 >= NT);
    // P1: Q00 even | stage B-q2,q3(t+1)
    ldAL(AsE); ldBL(BsE);
    stB(BsO, 2, t + 1); stB(BsO, 3, t + 1);
    SBAR(); mmQ(bfL, 0, 0); SBAR();
    // P2: Q01 even | stage A-q0,q2(t+2)
    ldBR(BsE);
    if (!last) { stA(AsE, 0, t + 2); stA(AsE, 2, t + 2); }
    SBAR(); mmQ(bfR, 0, 2); SBAR();
    // P3: Q10 even | stage B-q0,q1(t+2)
    ldAH(AsE);
    if (!last) { stB(BsE, 0, t + 2); stB(BsE, 1, t + 2); }
    SBAR(); mmQ(bfL, 4, 0); SBAR();
    // P4: Q11 even | stage A-q1,q3(t+2) | vmcnt
    if (!last) {
      stA(AsE, 1, t + 2); stA(AsE, 3, t + 2);
      asm volatile("s_waitcnt vmcnt(6)" ::: "memory");
    } else {
      asm volatile("s_waitcnt vmcnt(0)" ::: "memory");
    }
    SBAR(); mmQ(bfR, 4, 2); SBAR();
    // P5: Q00 odd | stage B-q2,q3(t+2)
    ldAL(AsO); ldBL(BsO);
    if (!last) { stB(BsE, 2, t + 2); stB(BsE, 3, t + 2); }
    SBAR(); mmQ(bfL, 0, 0); SBAR();
    // P6: Q01 odd | stage A-q0,q2(t+3)
    ldBR(BsO);
    if (!last) { stA(AsO, 0, t + 3); stA(AsO, 2, t + 3); }
    SBAR(); mmQ(bfR, 0, 2); SBAR();
    // P7: Q10 odd | stage B-q0,q1(t+3)
    ldAH(AsO);
    if (!last) { stB(BsO, 0, t + 3); stB(BsO, 1, t + 3); }
    SBAR(); mmQ(bfL, 4, 0); SBAR();
    // P8: Q11 odd | stage A-q1,q3(t+3) | vmcnt
    if (!last) {
      stA(AsO, 1, t + 3); stA(AsO, 3, t + 3);
      asm volatile("s_waitcnt vmcnt(6)" ::: "memory");
    }
    SBAR(); mmQ(bfR, 4, 2); SBAR();
  }

  const int r4 = hi * 4;
#pragma unroll
  for (int mi = 0; mi < 8; ++mi) {
#pragma unroll
    for (int nj = 0; nj < 4; ++nj) {
      const int cg = n0 + wc * 64 + nj * 16 + ro;
      const float bv = bias[cg];
#pragma unroll
      for (int q = 0; q < 4; ++q) {
        const int rg = m0 + wr * 128 + mi * 16 + r4 + q;
        const float v = acc[mi][nj][q] + bv;
        out0[(size_t)rg * N + cg] = f2b(EPI == 1 ? fmaxf(v, 0.f) : v);
      }
    }
  }
}

// ---------------- skinny GEMM (R7 structure, BM=128, BN=64) ----------------

enum { EPI_BF16 = 0, EPI_RELU_BF16 = 1, EPI_RES = 2, EPI_RES2 = 3 };

template<int EPI, int BM, int BN>
__global__ void gemm_bt(const unsigned short* __restrict__ A,
                        const unsigned short* __restrict__ Bw,
                        const float* __restrict__ bias,
                        int N, int K, int nn,
                        void* out0, const float* res, float* out1) {
  constexpr int MI = BM / 32;
  constexpr int NJ = BN / 32;
  __shared__ alignas(16) unsigned short As[2][BM * 64];
  __shared__ alignas(16) unsigned short Bs[2][BN * 64];
  const int tid = threadIdx.x;
  const int lane = tid & 63;
  const int wave = tid >> 6;
  int id = blockIdx.x;
  const int nwg = gridDim.x;
  id = (id & 7) * (nwg >> 3) + (id >> 3);
  const int bx = id % nn;
  const int by = id / nn;
  const int m0 = by * BM;
  const int n0 = bx * BN;
  const int wm = (wave >> 1) * (BM / 2);
  const int wn = (wave & 1) * (BN / 2);

  auto stage = [&](int buf, int kt) {
    const size_t k0 = (size_t)kt * 64;
#pragma unroll
    for (int i = 0; i < MI; ++i) {
      const int c = tid + 256 * i;
      const int row = c >> 3;
      const int lc = (c & 7) ^ (row & 7);
      gload16(A + (size_t)(m0 + row) * K + k0 + lc * 8, &As[buf][c * 8]);
    }
#pragma unroll
    for (int i = 0; i < NJ; ++i) {
      const int c = tid + 256 * i;
      const int row = c >> 3;
      const int lc = (c & 7) ^ (row & 7);
      gload16(Bw + (size_t)(n0 + row) * K + k0 + lc * 8, &Bs[buf][c * 8]);
    }
  };

  f32x4 acc[MI][NJ];
#pragma unroll
  for (int i = 0; i < MI; ++i)
#pragma unroll
    for (int j = 0; j < NJ; ++j) acc[i][j] = f32x4{0.f, 0.f, 0.f, 0.f};

  const int nk = K >> 6;
  stage(0, 0);
  int cur = 0;
  const int ro = lane & 15;
  const int hi = lane >> 4;
  for (int kt = 0; kt < nk; ++kt) {
    __syncthreads();
    if (kt + 1 < nk) stage(cur ^ 1, kt + 1);
    bf16x8 af[MI][2], bf[NJ][2];
#pragma unroll
    for (int i = 0; i < MI; ++i) {
      const int r = wm + i * 16 + ro;
#pragma unroll
      for (int ks = 0; ks < 2; ++ks)
        af[i][ks] = *(const bf16x8*)&As[cur][r * 64 + (((ks << 2) + hi) ^ (r & 7)) * 8];
    }
#pragma unroll
    for (int j = 0; j < NJ; ++j) {
      const int r = wn + j * 16 + ro;
#pragma unroll
      for (int ks = 0; ks < 2; ++ks)
        bf[j][ks] = *(const bf16x8*)&Bs[cur][r * 64 + (((ks << 2) + hi) ^ (r & 7)) * 8];
    }
#pragma unroll
    for (int ks = 0; ks < 2; ++ks)
#pragma unroll
      for (int i = 0; i < MI; ++i)
#pragma unroll
        for (int j = 0; j < NJ; ++j)
          acc[i][j] = __builtin_amdgcn_mfma_f32_16x16x32_bf16(af[i][ks], bf[j][ks], acc[i][j], 0, 0, 0);
    cur ^= 1;
  }

  const int r4 = hi * 4;
#pragma unroll
  for (int i = 0; i < MI; ++i) {
#pragma unroll
    for (int j = 0; j < NJ; ++j) {
      const int cg = n0 + wn + j * 16 + ro;
      const float bv = bias[cg];
#pragma unroll
      for (int q = 0; q < 4; ++q) {
        const int rg = m0 + wm + i * 16 + r4 + q;
        const size_t idx = (size_t)rg * N + cg;
        const float v = acc[i][j][q] + bv;
        if (EPI == EPI_BF16) {
          ((unsigned short*)out0)[idx] = f2b(v);
        } else if (EPI == EPI_RELU_BF16) {
          ((unsigned short*)out0)[idx] = f2b(fmaxf(v, 0.f));
        } else if (EPI == EPI_RES) {
          ((float*)out0)[idx] = res[idx] + v;
        } else {
          const float r = res[idx];
          ((float*)out0)[idx] = v;
          out1[idx] = r + v;
        }
      }
    }
  }
}

// ---------------- fused flash attention (4-wave, LDS-staged K/V) ----------------

template<bool CAUSAL>
__global__ __launch_bounds__(256) void attn_kernel(
    const unsigned short* __restrict__ Qg, int qs,
    const unsigned short* __restrict__ Kg, int ksd,
    const unsigned short* __restrict__ Vt,
    unsigned short* __restrict__ Og) {
  __shared__ alignas(16) unsigned short Ks[2][64 * 64];
  __shared__ alignas(16) unsigned short Vs[2][64 * 64];
  __shared__ alignas(16) unsigned short Pl[4][32 * 64];
  const int qt0 = blockIdx.x;
  const int h  = blockIdx.y;
  const int b  = blockIdx.z;
  const int tid = threadIdx.x;
  const int lane = tid & 63;
  const int w = tid >> 6;
  const int ro = lane & 15;
  const int hi = lane >> 4;
  const int qrow0 = qt0 * 128 + w * 32;
  const size_t qbase = (size_t)b * 512 * qs  + (size_t)h * 64;
  const size_t kbase = (size_t)b * 512 * ksd + (size_t)h * 64;
  const size_t vbase = ((size_t)(b * 16 + h)) * 64 * 512;
  const size_t obase = (size_t)b * 512 * 1024 + (size_t)h * 64;

  bf16x8 qf[2][2];
#pragma unroll
  for (int mi = 0; mi < 2; ++mi)
#pragma unroll
    for (int ks = 0; ks < 2; ++ks)
      qf[mi][ks] = *(const bf16x8*)&Qg[qbase + (size_t)(qrow0 + mi * 16 + ro) * qs + ks * 32 + hi * 8];

  f32x4 o[2][4];
  float mrun[2][4], lrun[2][4];
#pragma unroll
  for (int mi = 0; mi < 2; ++mi) {
#pragma unroll
    for (int di = 0; di < 4; ++di) o[mi][di] = f32x4{0.f, 0.f, 0.f, 0.f};
#pragma unroll
    for (int q = 0; q < 4; ++q) { mrun[mi][q] = -1e30f; lrun[mi][q] = 0.f; }
  }

  auto stage = [&](int buf, int kt) {
#pragma unroll
    for (int i = 0; i < 2; ++i) {
      const int c = tid + 256 * i;
      const int row = c >> 3;
      const int lc = (c & 7) ^ (row & 7);
      gload16(Kg + kbase + (size_t)(kt * 64 + row) * ksd + lc * 8, &Ks[buf][c * 8]);
    }
#pragma unroll
    for (int i = 0; i < 2; ++i) {
      const int c = tid + 256 * i;
      const int row = c >> 3;
      const int lc = (c & 7) ^ (row & 7);
      gload16(Vt + vbase + (size_t)row * 512 + (size_t)kt * 64 + lc * 8, &Vs[buf][c * 8]);
    }
  };

  const int ktmax = CAUSAL ? (qt0 * 2 + 1) : 7;
  stage(0, 0);
  int cur = 0;
  for (int kt = 0; kt <= ktmax; ++kt) {
    __syncthreads();
    if (kt < ktmax) stage(cur ^ 1, kt + 1);
    const bool skip = CAUSAL && (kt * 64 > qrow0 + 31);
    if (!skip) {
      bf16x8 kf[4][2];
#pragma unroll
      for (int ni = 0; ni < 4; ++ni) {
        const int r = ni * 16 + ro;
#pragma unroll
        for (int ks = 0; ks < 2; ++ks)
          kf[ni][ks] = *(const bf16x8*)&Ks[cur][r * 64 + (((ks << 2) + hi) ^ (r & 7)) * 8];
      }

      f32x4 s[2][4];
#pragma unroll
      for (int mi = 0; mi < 2; ++mi)
#pragma unroll
        for (int ni = 0; ni < 4; ++ni) s[mi][ni] = f32x4{0.f, 0.f, 0.f, 0.f};
#pragma unroll
      for (int ks = 0; ks < 2; ++ks)
#pragma unroll
        for (int mi = 0; mi < 2; ++mi)
#pragma unroll
          for (int ni = 0; ni < 4; ++ni)
            s[mi][ni] = __builtin_amdgcn_mfma_f32_16x16x32_bf16(qf[mi][ks], kf[ni][ks], s[mi][ni], 0, 0, 0);

      const bool dm = CAUSAL && (kt * 64 + 63 > qrow0);
#pragma unroll
      for (int mi = 0; mi < 2; ++mi)
#pragma unroll
        for (int ni = 0; ni < 4; ++ni)
#pragma unroll
          for (int q = 0; q < 4; ++q) {
            float e = s[mi][ni][q] * 0.125f;
            if (dm && (kt * 64 + ni * 16 + ro) > (qrow0 + mi * 16 + hi * 4 + q)) e = -1e9f;
            s[mi][ni][q] = e;
          }

      float fac[2][4];
#pragma unroll
      for (int mi = 0; mi < 2; ++mi)
#pragma unroll
        for (int q = 0; q < 4; ++q) {
          float rm = s[mi][0][q];
#pragma unroll
          for (int ni = 1; ni < 4; ++ni) rm = fmaxf(rm, s[mi][ni][q]);
          rm = wred_max16(rm);
          const float mn = fmaxf(mrun[mi][q], rm);
          fac[mi][q] = __expf(mrun[mi][q] - mn);
          mrun[mi][q] = mn;
        }
#pragma unroll
      for (int mi = 0; mi < 2; ++mi)
#pragma unroll
        for (int q = 0; q < 4; ++q) {
          float rs = 0.f;
#pragma unroll
          for (int ni = 0; ni < 4; ++ni) {
            const float pv = __expf(s[mi][ni][q] - mrun[mi][q]);
            s[mi][ni][q] = pv;
            rs += pv;
          }
          rs = wred_sum16(rs);
          lrun[mi][q] = lrun[mi][q] * fac[mi][q] + rs;
        }
#pragma unroll
      for (int mi = 0; mi < 2; ++mi)
#pragma unroll
        for (int di = 0; di < 4; ++di)
#pragma unroll
          for (int q = 0; q < 4; ++q) o[mi][di][q] *= fac[mi][q];

#pragma unroll
      for (int mi = 0; mi < 2; ++mi)
#pragma unroll
        for (int ni = 0; ni < 4; ++ni)
#pragma unroll
          for (int q = 0; q < 4; ++q) {
            const int row = mi * 16 + hi * 4 + q;
            const int col = ni * 16 + ro;
            const int sc  = ((col >> 3) ^ (row & 7)) * 8 + (col & 7);
            Pl[w][row * 64 + sc] = f2b(s[mi][ni][q]);
          }

      bf16x8 pa[2][2];
#pragma unroll
      for (int mi = 0; mi < 2; ++mi)
#pragma unroll
        for (int ks = 0; ks < 2; ++ks) {
          const int row = mi * 16 + ro;
          pa[mi][ks] = *(const bf16x8*)&Pl[w][row * 64 + (((ks << 2) + hi) ^ (row & 7)) * 8];
        }

#pragma unroll
      for (int di = 0; di < 4; ++di)
#pragma unroll
        for (int ks = 0; ks < 2; ++ks) {
          const int r = di * 16 + ro;
          const bf16x8 vf = *(const bf16x8*)&Vs[cur][r * 64 + (((ks << 2) + hi) ^ (r & 7)) * 8];
#pragma unroll
          for (int mi = 0; mi < 2; ++mi)
            o[mi][di] = __builtin_amdgcn_mfma_f32_16x16x32_bf16(pa[mi][ks], vf, o[mi][di], 0, 0, 0);
        }
    }
    cur ^= 1;
  }

#pragma unroll
  for (int mi = 0; mi < 2; ++mi)
#pragma unroll
    for (int di = 0; di < 4; ++di)
#pragma unroll
      for (int q = 0; q < 4; ++q) {
        const float val = o[mi][di][q] / lrun[mi][q];
        Og[obase + (size_t)(qrow0 + mi * 16 + hi * 4 + q) * 1024 + di * 16 + ro] = f2b(val);
      }
}

// ---------------- host orchestration ----------------

extern "C" void kernel_launch(void* const* d_in, const int* in_sizes, int n_in,
                              void* d_out, int out_size, void* d_ws, size_t ws_size,
                              hipStream_t stream) {
  (void)in_sizes; (void)n_in; (void)out_size; (void)ws_size;
  const int*   dec = (const int*)d_in[0];
  const float* enc = (const float*)d_in[2];
  const float* emb = (const float*)d_in[4];
  const float* pe  = (const float*)d_in[5];
  const float* wq  = (const float*)d_in[6];
  const float* bq  = (const float*)d_in[7];
  const float* wk  = (const float*)d_in[8];
  const float* bk  = (const float*)d_in[9];
  const float* wv  = (const float*)d_in[10];
  const float* bv  = (const float*)d_in[11];
  const float* wo  = (const float*)d_in[12];
  const float* bo  = (const float*)d_in[13];
  const float* w1  = (const float*)d_in[14];
  const float* b1  = (const float*)d_in[15];
  const float* w2  = (const float*)d_in[16];
  const float* b2  = (const float*)d_in[17];
  const float* lng = (const float*)d_in[18];
  const float* lnb = (const float*)d_in[19];

  const size_t SZ_ACT = 4194304ull;     // 4096*1024

  char* p = (char*)d_ws;
  auto alloc = [&](size_t bytes) { char* r = p; p += (bytes + 255) & ~(size_t)255; return r; };
  unsigned short* qkvw  = (unsigned short*)alloc(3ull * 3 * 1048576 * 2);  // [L][3072][1024]
  unsigned short* kvw   = (unsigned short*)alloc(3ull * 2 * 1048576 * 2);  // [6144][1024]
  unsigned short* wqxb  = (unsigned short*)alloc(3ull * 1048576 * 2);      // [L][1024][1024]
  unsigned short* Wob   = (unsigned short*)alloc(6291456ull * 2);          // [L][2][1024][1024]
  unsigned short* W1b   = (unsigned short*)alloc(12582912ull * 2);
  unsigned short* W2b   = (unsigned short*)alloc(12582912ull * 2);
  unsigned short* encb  = (unsigned short*)alloc(SZ_ACT * 2);
  float*          x     = (float*)alloc(SZ_ACT * 4);
  float*          c     = (float*)alloc(SZ_ACT * 4);
  unsigned short* hb    = (unsigned short*)alloc(SZ_ACT * 2);
  unsigned short* qkvb  = (unsigned short*)alloc(4096ull * 3072 * 2);
  unsigned short* kvb   = (unsigned short*)alloc(4096ull * 6144 * 2);      // merged 3-layer K/V
  unsigned short* qb    = (unsigned short*)alloc(SZ_ACT * 2);
  unsigned short* vtb   = (unsigned short*)alloc(SZ_ACT * 2);              // [B][H][64][512]
  unsigned short* mid   = (unsigned short*)alloc(4096ull * 4096 * 2);
  float*          qkvbias = (float*)alloc(3ull * 3072 * 4);
  float*          kvbias  = (float*)alloc(3ull * 2048 * 4);

  cvt_kernel<<<2048, 256, 0, stream>>>(wo, Wob, 1572864);
  cvt_kernel<<<2048, 256, 0, stream>>>(w1, W1b, 3145728);
  cvt_kernel<<<2048, 256, 0, stream>>>(w2, W2b, 3145728);
  cvt_kernel<<<2048, 256, 0, stream>>>(enc, encb, 1048576);
  pack_w<<<dim3(1024, 3, 3), 256, 0, stream>>>(wq, wk, wv, 0, qkvw, 3);
  pack_w<<<dim3(1024, 2, 3), 256, 0, stream>>>(wk, wv, wv, 1, kvw, 2);
  pack_w<<<dim3(1024, 1, 3), 256, 0, stream>>>(wq, wq, wq, 1, wqxb, 1);
  pack_bias<<<dim3(3, 3), 256, 0, stream>>>(bq, bk, bv, 0, qkvbias, 3);
  pack_bias<<<dim3(2, 3), 256, 0, stream>>>(bk, bv, bv, 1, kvbias, 2);
  embed_kernel<<<4096, 256, 0, stream>>>(dec, emb, pe, x);

  // merged cross-attn K/V for all 3 layers: [4096][6144]
  gemm8p<0><<<16 * 24, 512, 0, stream>>>(encb, kvw, kvbias, 6144, kvb);

  const dim3 gAttn(4, 16, 8);
  const dim3 gVt(8, 16, 8);

  for (int l = 0; l < 3; ++l) {
    const float* g0 = lng + (l * 3 + 0) * 1024; const float* e0 = lnb + (l * 3 + 0) * 1024;
    const float* g1 = lng + (l * 3 + 1) * 1024; const float* e1 = lnb + (l * 3 + 1) * 1024;
    const float* g2 = lng + (l * 3 + 2) * 1024; const float* e2 = lnb + (l * 3 + 2) * 1024;

    // ---- self-attention sublayer ----
    ln_kernel<<<4096, 64, 0, stream>>>(x, g0, e0, hb);
    gemm8p<0><<<16 * 12, 512, 0, stream>>>(hb, qkvw + (size_t)l * 3 * 1048576,
        qkvbias + l * 3072, 3072, qkvb);
    vt_kernel<<<gVt, 256, 0, stream>>>(qkvb + 2048, 3072, vtb);
    attn_kernel<true><<<gAttn, 256, 0, stream>>>(qkvb, 3072, qkvb + 1024, 3072, vtb, hb);
    gemm_bt<EPI_RES, 128, 64><<<32 * 16, 256, 0, stream>>>(hb, Wob + (size_t)(l * 2) * 1048576,
        bo + (l * 2) * 1024, 1024, 1024, 16, x, x, nullptr);

    // ---- cross-attention sublayer ----
    ln_kernel<<<4096, 64, 0, stream>>>(x, g1, e1, hb);
    gemm_bt<EPI_BF16, 128, 64><<<32 * 16, 256, 0, stream>>>(hb, wqxb + (size_t)l * 1048576,
        bq + (l * 2 + 1) * 1024, 1024, 1024, 16, qb, nullptr, nullptr);
    vt_kernel<<<gVt, 256, 0, stream>>>(kvb + l * 2048 + 1024, 6144, vtb);
    attn_kernel<false><<<gAttn, 256, 0, stream>>>(qb, 1024, kvb + l * 2048, 6144, vtb, hb);
    gemm_bt<EPI_RES2, 128, 64><<<32 * 16, 256, 0, stream>>>(hb, Wob + (size_t)(l * 2 + 1) * 1048576,
        bo + (l * 2 + 1) * 1024, 1024, 1024, 16, c, x, x);

    // ---- FFN sublayer (residual is c, per reference quirk) ----
    ln_kernel<<<4096, 64, 0, stream>>>(x, g2, e2, hb);
    gemm8p<1><<<16 * 16, 512, 0, stream>>>(hb, W1b + (size_t)l * 4194304,
        b1 + l * 4096, 4096, mid);
    float* xout = (l == 2) ? (float*)d_out : x;
    gemm_bt<EPI_RES, 128, 64><<<32 * 16, 256, 0, stream>>>(mid, W2b + (size_t)l * 4194304,
        b2 + l * 1024, 1024, 4096, 16, xout, c, nullptr);
  }
}

// Round 15
// 1072.642 us; speedup vs baseline: 1.1242x; 1.0370x over previous
//
#include <hip/hip_runtime.h>
#include <hip/hip_bf16.h>

using bf16x8 = __attribute__((ext_vector_type(8))) short;
using f32x4  = __attribute__((ext_vector_type(4))) float;
using u16x4  = __attribute__((ext_vector_type(4))) unsigned short;

#define DEVI static __device__ __forceinline__
#define SBAR() asm volatile("s_barrier" ::: "memory")

DEVI unsigned short f2b(float f) {           // f32 -> bf16 RNE
  unsigned int u = __float_as_uint(f);
  u += 0x7FFFu + ((u >> 16) & 1u);
  return (unsigned short)(u >> 16);
}

DEVI void gload16(const unsigned short* g, unsigned short* l) {
  __builtin_amdgcn_global_load_lds(
      (const __attribute__((address_space(1))) unsigned int*)g,
      (__attribute__((address_space(3))) unsigned int*)l, 16, 0, 0);
}

DEVI float wred_max16(float v) {
#pragma unroll
  for (int m = 1; m < 16; m <<= 1) v = fmaxf(v, __shfl_xor(v, m, 64));
  return v;
}
DEVI float wred_sum16(float v) {
#pragma unroll
  for (int m = 1; m < 16; m <<= 1) v += __shfl_xor(v, m, 64);
  return v;
}

// ---------------- elementwise / pack kernels ----------------

__global__ void cvt_kernel(const float* __restrict__ in,
                           unsigned short* __restrict__ out, int n4) {
  int i = blockIdx.x * blockDim.x + threadIdx.x;
  const int stride = gridDim.x * blockDim.x;
  for (; i < n4; i += stride) {
    const float4 v = ((const float4*)in)[i];
    u16x4 o;
    o[0] = f2b(v.x); o[1] = f2b(v.y); o[2] = f2b(v.z); o[3] = f2b(v.w);
    ((u16x4*)out)[i] = o;
  }
}

__global__ void pack_w(const float* __restrict__ s0,
                       const float* __restrict__ s1,
                       const float* __restrict__ s2,
                       int sub, unsigned short* __restrict__ dst, int nm) {
  const int r = blockIdx.x;
  const int m = blockIdx.y;
  const int l = blockIdx.z;
  const float* src = (m == 0 ? s0 : m == 1 ? s1 : s2)
                   + (size_t)(l * 2 + sub) * 1048576 + (size_t)r * 1024;
  unsigned short* d = dst + ((size_t)(l * nm + m) * 1024 + r) * 1024;
  const int col = threadIdx.x * 4;
  const float4 v = *(const float4*)(src + col);
  u16x4 o;
  o[0] = f2b(v.x); o[1] = f2b(v.y); o[2] = f2b(v.z); o[3] = f2b(v.w);
  *(u16x4*)(d + col) = o;
}

__global__ void pack_bias(const float* __restrict__ s0,
                          const float* __restrict__ s1,
                          const float* __restrict__ s2,
                          int sub, float* __restrict__ dst, int nm) {
  const int m = blockIdx.x, l = blockIdx.y;
  const float* src = (m == 0 ? s0 : m == 1 ? s1 : s2) + (size_t)(l * 2 + sub) * 1024;
  float* d = dst + ((size_t)l * nm + m) * 1024;
  const int i = threadIdx.x * 4;
  *(float4*)(d + i) = *(const float4*)(src + i);
}

__global__ void embed_kernel(const int* __restrict__ ids,
                             const float* __restrict__ emb,
                             const float* __restrict__ pe,
                             float* __restrict__ x) {
  const int row = blockIdx.x;
  const int t = row & 511;
  const int col = threadIdx.x * 4;
  const int id = ids[row];
  const float4 e = *(const float4*)(emb + (size_t)id * 1024 + col);
  const float4 p = *(const float4*)(pe + (size_t)t * 1024 + col);
  float4 o;
  o.x = e.x * 32.f + p.x; o.y = e.y * 32.f + p.y;
  o.z = e.z * 32.f + p.z; o.w = e.w * 32.f + p.w;
  *(float4*)(x + (size_t)row * 1024 + col) = o;
}

__global__ void ln_kernel(const float* __restrict__ x,
                          const float* __restrict__ g,
                          const float* __restrict__ b,
                          unsigned short* __restrict__ out) {
  const int row = blockIdx.x;
  const int l = threadIdx.x;
  const float4* xr = (const float4*)(x + (size_t)row * 1024);
  float4 v[4];
  float s = 0.f;
#pragma unroll
  for (int i = 0; i < 4; ++i) {
    v[i] = xr[l * 4 + i];
    s += v[i].x + v[i].y + v[i].z + v[i].w;
  }
#pragma unroll
  for (int m = 1; m < 64; m <<= 1) s += __shfl_xor(s, m, 64);
  const float mean = s * (1.f / 1024.f);
  float vs = 0.f;
#pragma unroll
  for (int i = 0; i < 4; ++i) {
    float dx = v[i].x - mean, dy = v[i].y - mean, dz = v[i].z - mean, dw = v[i].w - mean;
    vs += dx * dx + dy * dy + dz * dz + dw * dw;
  }
#pragma unroll
  for (int m = 1; m < 64; m <<= 1) vs += __shfl_xor(vs, m, 64);
  const float inv = rsqrtf(vs * (1.f / 1024.f) + 1e-5f);
#pragma unroll
  for (int i = 0; i < 4; ++i) {
    const int col = l * 16 + i * 4;
    const float4 gg = *(const float4*)(g + col);
    const float4 bb = *(const float4*)(b + col);
    u16x4 o;
    o[0] = f2b((v[i].x - mean) * inv * gg.x + bb.x);
    o[1] = f2b((v[i].y - mean) * inv * gg.y + bb.y);
    o[2] = f2b((v[i].z - mean) * inv * gg.z + bb.z);
    o[3] = f2b((v[i].w - mean) * inv * gg.w + bb.w);
    *(u16x4*)(out + (size_t)row * 1024 + col) = o;
  }
}

// Transpose per-head V into Vt[b][h][d=64][t=512] for vectorized PV loads.
__global__ void vt_kernel(const unsigned short* __restrict__ Vsrc, int vsd,
                          unsigned short* __restrict__ Vt) {
  __shared__ alignas(16) unsigned short t[64][72];
  const int tt = blockIdx.x;
  const int h  = blockIdx.y;
  const int b  = blockIdx.z;
  const int tid = threadIdx.x;
  const int r  = tid >> 2;
  const int ch = tid & 3;
  const unsigned short* src =
      Vsrc + (size_t)(b * 512 + tt * 64 + r) * vsd + (size_t)h * 64 + ch * 16;
  const bf16x8 v0 = *(const bf16x8*)src;
  const bf16x8 v1 = *(const bf16x8*)(src + 8);
#pragma unroll
  for (int j = 0; j < 8; ++j) {
    t[ch * 16 + j][r]     = (unsigned short)v0[j];
    t[ch * 16 + 8 + j][r] = (unsigned short)v1[j];
  }
  __syncthreads();
  const int d  = tid >> 2;
  const int tp = tid & 3;
  unsigned short* dst = Vt + (((size_t)(b * 16 + h) * 64 + d) * 512) + tt * 64 + tp * 16;
  *(bf16x8*)dst       = *(const bf16x8*)&t[d][tp * 16];
  *(bf16x8*)(dst + 8) = *(const bf16x8*)&t[d][tp * 16 + 8];
}

// ------------- 8-phase fat GEMM core: 256x256 tile, 8 waves (m201 port) -------------
// Processes K-range [kofs, kofs+1024) of row-major A (lda) and Bw (ldb).
// 8 waves = 2M x 4N, wave tile 128x64. Per iteration 2 ktiles, 8 phases of
// {ds-read subtile | 2 quarter global_load_lds | barrier | 16 MFMA setprio |
//  barrier}; counted vmcnt(6) at phases 4/8 only. Region-safe stage schedule.

struct G8POut { f32x4 acc[8][4]; int m0, n0, wr, wc, ro, hi; };

template<int LDA, int LDB>
DEVI void gemm8p_core(const unsigned short* __restrict__ A,
                      const unsigned short* __restrict__ Bw,
                      int m0, int n0, int kofs,
                      unsigned short* AsE, unsigned short* BsE,
                      unsigned short* AsO, unsigned short* BsO,
                      int tid, f32x4 (&acc)[8][4]) {
  constexpr int NT = 16;
  const int lane = tid & 63;
  const int wave = tid >> 6;
  const int wr = wave >> 2;
  const int wc = wave & 3;
  const int ro = lane & 15;
  const int hi = lane >> 4;

  auto stA = [&](unsigned short* buf, int q, int kt) {
    const int row = tid >> 3;
    const int lc = (tid & 7) ^ (row & 7);
    gload16(A + (size_t)(m0 + q * 64 + row) * LDA + kofs + kt * 64 + lc * 8,
            buf + q * 4096 + tid * 8);
  };
  auto stB = [&](unsigned short* buf, int q, int kt) {
    const int row = tid >> 3;
    const int lc = (tid & 7) ^ (row & 7);
    gload16(Bw + (size_t)(n0 + q * 64 + row) * LDB + kofs + kt * 64 + lc * 8,
            buf + q * 4096 + tid * 8);
  };

  bf16x8 af[4][2], bfL[2][2], bfR[2][2];
  auto ldAL = [&](const unsigned short* buf) {
#pragma unroll
    for (int mi = 0; mi < 4; ++mi) {
      const int r = wr * 128 + mi * 16 + ro;
#pragma unroll
      for (int ks = 0; ks < 2; ++ks)
        af[mi][ks] = *(const bf16x8*)&buf[r * 64 + (((ks << 2) + hi) ^ (r & 7)) * 8];
    }
  };
  auto ldAH = [&](const unsigned short* buf) {
#pragma unroll
    for (int mi = 0; mi < 4; ++mi) {
      const int r = wr * 128 + 64 + mi * 16 + ro;
#pragma unroll
      for (int ks = 0; ks < 2; ++ks)
        af[mi][ks] = *(const bf16x8*)&buf[r * 64 + (((ks << 2) + hi) ^ (r & 7)) * 8];
    }
  };
  auto ldBL = [&](const unsigned short* buf) {
#pragma unroll
    for (int nj = 0; nj < 2; ++nj) {
      const int r = wc * 64 + nj * 16 + ro;
#pragma unroll
      for (int ks = 0; ks < 2; ++ks)
        bfL[nj][ks] = *(const bf16x8*)&buf[r * 64 + (((ks << 2) + hi) ^ (r & 7)) * 8];
    }
  };
  auto ldBR = [&](const unsigned short* buf) {
#pragma unroll
    for (int nj = 0; nj < 2; ++nj) {
      const int r = wc * 64 + 32 + nj * 16 + ro;
#pragma unroll
      for (int ks = 0; ks < 2; ++ks)
        bfR[nj][ks] = *(const bf16x8*)&buf[r * 64 + (((ks << 2) + hi) ^ (r & 7)) * 8];
    }
  };
  auto mmQ = [&](bf16x8 (&bf)[2][2], int mo, int no) {
    __builtin_amdgcn_s_setprio(1);
#pragma unroll
    for (int ks = 0; ks < 2; ++ks)
#pragma unroll
      for (int mi = 0; mi < 4; ++mi)
#pragma unroll
        for (int nj = 0; nj < 2; ++nj)
          acc[mo + mi][no + nj] =
              __builtin_amdgcn_mfma_f32_16x16x32_bf16(af[mi][ks], bf[nj][ks],
                                                      acc[mo + mi][no + nj], 0, 0, 0);
    __builtin_amdgcn_s_setprio(0);
  };

  stA(AsE, 0, 0); stA(AsE, 1, 0); stA(AsE, 2, 0); stA(AsE, 3, 0);
  stB(BsE, 0, 0); stB(BsE, 1, 0); stB(BsE, 2, 0); stB(BsE, 3, 0);
  stA(AsO, 0, 1); stA(AsO, 1, 1); stA(AsO, 2, 1); stA(AsO, 3, 1);
  stB(BsO, 0, 1); stB(BsO, 1, 1);
  asm volatile("s_waitcnt vmcnt(0)" ::: "memory");
  SBAR();

  for (int t = 0; t < NT; t += 2) {
    const bool last = (t + 2 >= NT);
    ldAL(AsE); ldBL(BsE);
    stB(BsO, 2, t + 1); stB(BsO, 3, t + 1);
    SBAR(); mmQ(bfL, 0, 0); SBAR();
    ldBR(BsE);
    if (!last) { stA(AsE, 0, t + 2); stA(AsE, 2, t + 2); }
    SBAR(); mmQ(bfR, 0, 2); SBAR();
    ldAH(AsE);
    if (!last) { stB(BsE, 0, t + 2); stB(BsE, 1, t + 2); }
    SBAR(); mmQ(bfL, 4, 0); SBAR();
    if (!last) {
      stA(AsE, 1, t + 2); stA(AsE, 3, t + 2);
      asm volatile("s_waitcnt vmcnt(6)" ::: "memory");
    } else {
      asm volatile("s_waitcnt vmcnt(0)" ::: "memory");
    }
    SBAR(); mmQ(bfR, 4, 2); SBAR();
    ldAL(AsO); ldBL(BsO);
    if (!last) { stB(BsE, 2, t + 2); stB(BsE, 3, t + 2); }
    SBAR(); mmQ(bfL, 0, 0); SBAR();
    ldBR(BsO);
    if (!last) { stA(AsO, 0, t + 3); stA(AsO, 2, t + 3); }
    SBAR(); mmQ(bfR, 0, 2); SBAR();
    ldAH(AsO);
    if (!last) { stB(BsO, 0, t + 3); stB(BsO, 1, t + 3); }
    SBAR(); mmQ(bfL, 4, 0); SBAR();
    if (!last) {
      stA(AsO, 1, t + 3); stA(AsO, 3, t + 3);
      asm volatile("s_waitcnt vmcnt(6)" ::: "memory");
    }
    SBAR(); mmQ(bfR, 4, 2); SBAR();
  }
}

template<int EPI>  // 0 = bf16, 1 = relu+bf16
__global__ __launch_bounds__(512, 1) void gemm8p(
    const unsigned short* __restrict__ A,
    const unsigned short* __restrict__ Bw,
    const float* __restrict__ bias,
    int N, unsigned short* __restrict__ out0) {
  __shared__ alignas(16) unsigned short AsE[256 * 64];
  __shared__ alignas(16) unsigned short BsE[256 * 64];
  __shared__ alignas(16) unsigned short AsO[256 * 64];
  __shared__ alignas(16) unsigned short BsO[256 * 64];
  const int tid = threadIdx.x;
  int id = blockIdx.x;
  const int nwg = gridDim.x;
  id = (id & 7) * (nwg >> 3) + (id >> 3);
  const int nn = N >> 8;
  const int bx = id % nn;
  const int by = id / nn;
  const int m0 = by * 256;
  const int n0 = bx * 256;

  f32x4 acc[8][4];
#pragma unroll
  for (int i = 0; i < 8; ++i)
#pragma unroll
    for (int j = 0; j < 4; ++j) acc[i][j] = f32x4{0.f, 0.f, 0.f, 0.f};

  gemm8p_core<1024, 1024>(A, Bw, m0, n0, 0, AsE, BsE, AsO, BsO, tid, acc);

  const int lane = tid & 63;
  const int wave = tid >> 6;
  const int wr = wave >> 2, wc = wave & 3;
  const int ro = lane & 15, hi = lane >> 4;
  const int r4 = hi * 4;
#pragma unroll
  for (int mi = 0; mi < 8; ++mi) {
#pragma unroll
    for (int nj = 0; nj < 4; ++nj) {
      const int cg = n0 + wc * 64 + nj * 16 + ro;
      const float bv = bias[cg];
#pragma unroll
      for (int q = 0; q < 4; ++q) {
        const int rg = m0 + wr * 128 + mi * 16 + r4 + q;
        const float v = acc[mi][nj][q] + bv;
        out0[(size_t)rg * N + cg] = f2b(EPI == 1 ? fmaxf(v, 0.f) : v);
      }
    }
  }
}

// FFN2 split-K=4: A=mid [4096][4096], Bw=W2 [1024][4096]; split s owns
// K-range [s*1024,(s+1)*1024). 64 tile-positions x 4 splits = 256 blocks.
// Writes f32 partial pbuf[s][4096][1024].
__global__ __launch_bounds__(512, 1) void gemm_sk8(
    const unsigned short* __restrict__ A,
    const unsigned short* __restrict__ Bw,
    float* __restrict__ pbuf) {
  __shared__ alignas(16) unsigned short AsE[256 * 64];
  __shared__ alignas(16) unsigned short BsE[256 * 64];
  __shared__ alignas(16) unsigned short AsO[256 * 64];
  __shared__ alignas(16) unsigned short BsO[256 * 64];
  const int tid = threadIdx.x;
  int id = blockIdx.x;
  const int nwg = gridDim.x;               // 256
  id = (id & 7) * (nwg >> 3) + (id >> 3);  // XCD swizzle
  const int s  = id >> 6;                  // split 0..3
  const int r6 = id & 63;
  const int bx = r6 & 3;                   // 4 col tiles (N=1024)
  const int by = r6 >> 2;                  // 16 row tiles
  const int m0 = by * 256;
  const int n0 = bx * 256;

  f32x4 acc[8][4];
#pragma unroll
  for (int i = 0; i < 8; ++i)
#pragma unroll
    for (int j = 0; j < 4; ++j) acc[i][j] = f32x4{0.f, 0.f, 0.f, 0.f};

  gemm8p_core<4096, 4096>(A, Bw, m0, n0, s * 1024, AsE, BsE, AsO, BsO, tid, acc);

  float* out = pbuf + (size_t)s * 4096 * 1024;
  const int lane = tid & 63;
  const int wave = tid >> 6;
  const int wr = wave >> 2, wc = wave & 3;
  const int ro = lane & 15, hi = lane >> 4;
  const int r4 = hi * 4;
#pragma unroll
  for (int mi = 0; mi < 8; ++mi)
#pragma unroll
    for (int nj = 0; nj < 4; ++nj) {
      const int cg = n0 + wc * 64 + nj * 16 + ro;
#pragma unroll
      for (int q = 0; q < 4; ++q) {
        const int rg = m0 + wr * 128 + mi * 16 + r4 + q;
        out[(size_t)rg * 1024 + cg] = acc[mi][nj][q];
      }
    }
}

// xout = c + p0 + p1 + p2 + p3 + bias   (f32, vectorized)
__global__ void reduce4_kernel(const float* __restrict__ c,
                               const float* __restrict__ pbuf,
                               const float* __restrict__ bias,
                               float* __restrict__ xout) {
  const int n4 = 4096 * 1024 / 4;
  int i = blockIdx.x * blockDim.x + threadIdx.x;
  const int stride = gridDim.x * blockDim.x;
  const float4* p0 = (const float4*)pbuf;
  const float4* p1 = (const float4*)(pbuf + 4194304);
  const float4* p2 = (const float4*)(pbuf + 2 * 4194304);
  const float4* p3 = (const float4*)(pbuf + 3 * 4194304);
  for (; i < n4; i += stride) {
    const float4 cc = ((const float4*)c)[i];
    const float4 a0 = p0[i];
    const float4 a1 = p1[i];
    const float4 a2 = p2[i];
    const float4 a3 = p3[i];
    const float4 bb = ((const float4*)bias)[i & 255];
    float4 o;
    o.x = cc.x + (a0.x + a1.x) + (a2.x + a3.x) + bb.x;
    o.y = cc.y + (a0.y + a1.y) + (a2.y + a3.y) + bb.y;
    o.z = cc.z + (a0.z + a1.z) + (a2.z + a3.z) + bb.z;
    o.w = cc.w + (a0.w + a1.w) + (a2.w + a3.w) + bb.w;
    ((float4*)xout)[i] = o;
  }
}

// ---------------- skinny GEMM (R7 structure, BM=128, BN=64) ----------------

enum { EPI_BF16 = 0, EPI_RELU_BF16 = 1, EPI_RES = 2, EPI_RES2 = 3 };

template<int EPI, int BM, int BN>
__global__ void gemm_bt(const unsigned short* __restrict__ A,
                        const unsigned short* __restrict__ Bw,
                        const float* __restrict__ bias,
                        int N, int K, int nn,
                        void* out0, const float* res, float* out1) {
  constexpr int MI = BM / 32;
  constexpr int NJ = BN / 32;
  __shared__ alignas(16) unsigned short As[2][BM * 64];
  __shared__ alignas(16) unsigned short Bs[2][BN * 64];
  const int tid = threadIdx.x;
  const int lane = tid & 63;
  const int wave = tid >> 6;
  int id = blockIdx.x;
  const int nwg = gridDim.x;
  id = (id & 7) * (nwg >> 3) + (id >> 3);
  const int bx = id % nn;
  const int by = id / nn;
  const int m0 = by * BM;
  const int n0 = bx * BN;
  const int wm = (wave >> 1) * (BM / 2);
  const int wn = (wave & 1) * (BN / 2);

  auto stage = [&](int buf, int kt) {
    const size_t k0 = (size_t)kt * 64;
#pragma unroll
    for (int i = 0; i < MI; ++i) {
      const int c = tid + 256 * i;
      const int row = c >> 3;
      const int lc = (c & 7) ^ (row & 7);
      gload16(A + (size_t)(m0 + row) * K + k0 + lc * 8, &As[buf][c * 8]);
    }
#pragma unroll
    for (int i = 0; i < NJ; ++i) {
      const int c = tid + 256 * i;
      const int row = c >> 3;
      const int lc = (c & 7) ^ (row & 7);
      gload16(Bw + (size_t)(n0 + row) * K + k0 + lc * 8, &Bs[buf][c * 8]);
    }
  };

  f32x4 acc[MI][NJ];
#pragma unroll
  for (int i = 0; i < MI; ++i)
#pragma unroll
    for (int j = 0; j < NJ; ++j) acc[i][j] = f32x4{0.f, 0.f, 0.f, 0.f};

  const int nk = K >> 6;
  stage(0, 0);
  int cur = 0;
  const int ro = lane & 15;
  const int hi = lane >> 4;
  for (int kt = 0; kt < nk; ++kt) {
    __syncthreads();
    if (kt + 1 < nk) stage(cur ^ 1, kt + 1);
    bf16x8 af[MI][2], bf[NJ][2];
#pragma unroll
    for (int i = 0; i < MI; ++i) {
      const int r = wm + i * 16 + ro;
#pragma unroll
      for (int ks = 0; ks < 2; ++ks)
        af[i][ks] = *(const bf16x8*)&As[cur][r * 64 + (((ks << 2) + hi) ^ (r & 7)) * 8];
    }
#pragma unroll
    for (int j = 0; j < NJ; ++j) {
      const int r = wn + j * 16 + ro;
#pragma unroll
      for (int ks = 0; ks < 2; ++ks)
        bf[j][ks] = *(const bf16x8*)&Bs[cur][r * 64 + (((ks << 2) + hi) ^ (r & 7)) * 8];
    }
#pragma unroll
    for (int ks = 0; ks < 2; ++ks)
#pragma unroll
      for (int i = 0; i < MI; ++i)
#pragma unroll
        for (int j = 0; j < NJ; ++j)
          acc[i][j] = __builtin_amdgcn_mfma_f32_16x16x32_bf16(af[i][ks], bf[j][ks], acc[i][j], 0, 0, 0);
    cur ^= 1;
  }

  const int r4 = hi * 4;
#pragma unroll
  for (int i = 0; i < MI; ++i) {
#pragma unroll
    for (int j = 0; j < NJ; ++j) {
      const int cg = n0 + wn + j * 16 + ro;
      const float bv = bias[cg];
#pragma unroll
      for (int q = 0; q < 4; ++q) {
        const int rg = m0 + wm + i * 16 + r4 + q;
        const size_t idx = (size_t)rg * N + cg;
        const float v = acc[i][j][q] + bv;
        if (EPI == EPI_BF16) {
          ((unsigned short*)out0)[idx] = f2b(v);
        } else if (EPI == EPI_RELU_BF16) {
          ((unsigned short*)out0)[idx] = f2b(fmaxf(v, 0.f));
        } else if (EPI == EPI_RES) {
          ((float*)out0)[idx] = res[idx] + v;
        } else {
          const float r = res[idx];
          ((float*)out0)[idx] = v;
          out1[idx] = r + v;
        }
      }
    }
  }
}

// ---------------- fused flash attention (4-wave, LDS-staged K/V) ----------------

template<bool CAUSAL>
__global__ __launch_bounds__(256) void attn_kernel(
    const unsigned short* __restrict__ Qg, int qs,
    const unsigned short* __restrict__ Kg, int ksd,
    const unsigned short* __restrict__ Vt,
    unsigned short* __restrict__ Og) {
  __shared__ alignas(16) unsigned short Ks[2][64 * 64];
  __shared__ alignas(16) unsigned short Vs[2][64 * 64];
  __shared__ alignas(16) unsigned short Pl[4][32 * 64];
  const int qt0 = blockIdx.x;
  const int h  = blockIdx.y;
  const int b  = blockIdx.z;
  const int tid = threadIdx.x;
  const int lane = tid & 63;
  const int w = tid >> 6;
  const int ro = lane & 15;
  const int hi = lane >> 4;
  const int qrow0 = qt0 * 128 + w * 32;
  const size_t qbase = (size_t)b * 512 * qs  + (size_t)h * 64;
  const size_t kbase = (size_t)b * 512 * ksd + (size_t)h * 64;
  const size_t vbase = ((size_t)(b * 16 + h)) * 64 * 512;
  const size_t obase = (size_t)b * 512 * 1024 + (size_t)h * 64;

  bf16x8 qf[2][2];
#pragma unroll
  for (int mi = 0; mi < 2; ++mi)
#pragma unroll
    for (int ks = 0; ks < 2; ++ks)
      qf[mi][ks] = *(const bf16x8*)&Qg[qbase + (size_t)(qrow0 + mi * 16 + ro) * qs + ks * 32 + hi * 8];

  f32x4 o[2][4];
  float mrun[2][4], lrun[2][4];
#pragma unroll
  for (int mi = 0; mi < 2; ++mi) {
#pragma unroll
    for (int di = 0; di < 4; ++di) o[mi][di] = f32x4{0.f, 0.f, 0.f, 0.f};
#pragma unroll
    for (int q = 0; q < 4; ++q) { mrun[mi][q] = -1e30f; lrun[mi][q] = 0.f; }
  }

  auto stage = [&](int buf, int kt) {
#pragma unroll
    for (int i = 0; i < 2; ++i) {
      const int c = tid + 256 * i;
      const int row = c >> 3;
      const int lc = (c & 7) ^ (row & 7);
      gload16(Kg + kbase + (size_t)(kt * 64 + row) * ksd + lc * 8, &Ks[buf][c * 8]);
    }
#pragma unroll
    for (int i = 0; i < 2; ++i) {
      const int c = tid + 256 * i;
      const int row = c >> 3;
      const int lc = (c & 7) ^ (row & 7);
      gload16(Vt + vbase + (size_t)row * 512 + (size_t)kt * 64 + lc * 8, &Vs[buf][c * 8]);
    }
  };

  const int ktmax = CAUSAL ? (qt0 * 2 + 1) : 7;
  stage(0, 0);
  int cur = 0;
  for (int kt = 0; kt <= ktmax; ++kt) {
    __syncthreads();
    if (kt < ktmax) stage(cur ^ 1, kt + 1);
    const bool skip = CAUSAL && (kt * 64 > qrow0 + 31);
    if (!skip) {
      bf16x8 kf[4][2];
#pragma unroll
      for (int ni = 0; ni < 4; ++ni) {
        const int r = ni * 16 + ro;
#pragma unroll
        for (int ks = 0; ks < 2; ++ks)
          kf[ni][ks] = *(const bf16x8*)&Ks[cur][r * 64 + (((ks << 2) + hi) ^ (r & 7)) * 8];
      }

      f32x4 s[2][4];
#pragma unroll
      for (int mi = 0; mi < 2; ++mi)
#pragma unroll
        for (int ni = 0; ni < 4; ++ni) s[mi][ni] = f32x4{0.f, 0.f, 0.f, 0.f};
#pragma unroll
      for (int ks = 0; ks < 2; ++ks)
#pragma unroll
        for (int mi = 0; mi < 2; ++mi)
#pragma unroll
          for (int ni = 0; ni < 4; ++ni)
            s[mi][ni] = __builtin_amdgcn_mfma_f32_16x16x32_bf16(qf[mi][ks], kf[ni][ks], s[mi][ni], 0, 0, 0);

      const bool dm = CAUSAL && (kt * 64 + 63 > qrow0);
#pragma unroll
      for (int mi = 0; mi < 2; ++mi)
#pragma unroll
        for (int ni = 0; ni < 4; ++ni)
#pragma unroll
          for (int q = 0; q < 4; ++q) {
            float e = s[mi][ni][q] * 0.125f;
            if (dm && (kt * 64 + ni * 16 + ro) > (qrow0 + mi * 16 + hi * 4 + q)) e = -1e9f;
            s[mi][ni][q] = e;
          }

      float fac[2][4];
#pragma unroll
      for (int mi = 0; mi < 2; ++mi)
#pragma unroll
        for (int q = 0; q < 4; ++q) {
          float rm = s[mi][0][q];
#pragma unroll
          for (int ni = 1; ni < 4; ++ni) rm = fmaxf(rm, s[mi][ni][q]);
          rm = wred_max16(rm);
          const float mn = fmaxf(mrun[mi][q], rm);
          fac[mi][q] = __expf(mrun[mi][q] - mn);
          mrun[mi][q] = mn;
        }
#pragma unroll
      for (int mi = 0; mi < 2; ++mi)
#pragma unroll
        for (int q = 0; q < 4; ++q) {
          float rs = 0.f;
#pragma unroll
          for (int ni = 0; ni < 4; ++ni) {
            const float pv = __expf(s[mi][ni][q] - mrun[mi][q]);
            s[mi][ni][q] = pv;
            rs += pv;
          }
          rs = wred_sum16(rs);
          lrun[mi][q] = lrun[mi][q] * fac[mi][q] + rs;
        }
#pragma unroll
      for (int mi = 0; mi < 2; ++mi)
#pragma unroll
        for (int di = 0; di < 4; ++di)
#pragma unroll
          for (int q = 0; q < 4; ++q) o[mi][di][q] *= fac[mi][q];

#pragma unroll
      for (int mi = 0; mi < 2; ++mi)
#pragma unroll
        for (int ni = 0; ni < 4; ++ni)
#pragma unroll
          for (int q = 0; q < 4; ++q) {
            const int row = mi * 16 + hi * 4 + q;
            const int col = ni * 16 + ro;
            const int sc  = ((col >> 3) ^ (row & 7)) * 8 + (col & 7);
            Pl[w][row * 64 + sc] = f2b(s[mi][ni][q]);
          }

      bf16x8 pa[2][2];
#pragma unroll
      for (int mi = 0; mi < 2; ++mi)
#pragma unroll
        for (int ks = 0; ks < 2; ++ks) {
          const int row = mi * 16 + ro;
          pa[mi][ks] = *(const bf16x8*)&Pl[w][row * 64 + (((ks << 2) + hi) ^ (row & 7)) * 8];
        }

#pragma unroll
      for (int di = 0; di < 4; ++di)
#pragma unroll
        for (int ks = 0; ks < 2; ++ks) {
          const int r = di * 16 + ro;
          const bf16x8 vf = *(const bf16x8*)&Vs[cur][r * 64 + (((ks << 2) + hi) ^ (r & 7)) * 8];
#pragma unroll
          for (int mi = 0; mi < 2; ++mi)
            o[mi][di] = __builtin_amdgcn_mfma_f32_16x16x32_bf16(pa[mi][ks], vf, o[mi][di], 0, 0, 0);
        }
    }
    cur ^= 1;
  }

#pragma unroll
  for (int mi = 0; mi < 2; ++mi)
#pragma unroll
    for (int di = 0; di < 4; ++di)
#pragma unroll
      for (int q = 0; q < 4; ++q) {
        const float val = o[mi][di][q] / lrun[mi][q];
        Og[obase + (size_t)(qrow0 + mi * 16 + hi * 4 + q) * 1024 + di * 16 + ro] = f2b(val);
      }
}

// ---------------- host orchestration ----------------

extern "C" void kernel_launch(void* const* d_in, const int* in_sizes, int n_in,
                              void* d_out, int out_size, void* d_ws, size_t ws_size,
                              hipStream_t stream) {
  (void)in_sizes; (void)n_in; (void)out_size; (void)ws_size;
  const int*   dec = (const int*)d_in[0];
  const float* enc = (const float*)d_in[2];
  const float* emb = (const float*)d_in[4];
  const float* pe  = (const float*)d_in[5];
  const float* wq  = (const float*)d_in[6];
  const float* bq  = (const float*)d_in[7];
  const float* wk  = (const float*)d_in[8];
  const float* bk  = (const float*)d_in[9];
  const float* wv  = (const float*)d_in[10];
  const float* bv  = (const float*)d_in[11];
  const float* wo  = (const float*)d_in[12];
  const float* bo  = (const float*)d_in[13];
  const float* w1  = (const float*)d_in[14];
  const float* b1  = (const float*)d_in[15];
  const float* w2  = (const float*)d_in[16];
  const float* b2  = (const float*)d_in[17];
  const float* lng = (const float*)d_in[18];
  const float* lnb = (const float*)d_in[19];

  const size_t SZ_ACT = 4194304ull;     // 4096*1024

  char* p = (char*)d_ws;
  auto alloc = [&](size_t bytes) { char* r = p; p += (bytes + 255) & ~(size_t)255; return r; };
  unsigned short* qkvw  = (unsigned short*)alloc(3ull * 3 * 1048576 * 2);  // [L][3072][1024]
  unsigned short* kvw   = (unsigned short*)alloc(3ull * 2 * 1048576 * 2);  // [6144][1024]
  unsigned short* wqxb  = (unsigned short*)alloc(3ull * 1048576 * 2);      // [L][1024][1024]
  unsigned short* Wob   = (unsigned short*)alloc(6291456ull * 2);          // [L][2][1024][1024]
  unsigned short* W1b   = (unsigned short*)alloc(12582912ull * 2);
  unsigned short* W2b   = (unsigned short*)alloc(12582912ull * 2);
  unsigned short* encb  = (unsigned short*)alloc(SZ_ACT * 2);
  float*          x     = (float*)alloc(SZ_ACT * 4);
  float*          c     = (float*)alloc(SZ_ACT * 4);
  unsigned short* hb    = (unsigned short*)alloc(SZ_ACT * 2);
  unsigned short* qkvb  = (unsigned short*)alloc(4096ull * 3072 * 2);
  unsigned short* kvb   = (unsigned short*)alloc(4096ull * 6144 * 2);      // merged 3-layer K/V
  unsigned short* qb    = (unsigned short*)alloc(SZ_ACT * 2);
  unsigned short* vtb   = (unsigned short*)alloc(SZ_ACT * 2);              // [B][H][64][512]
  unsigned short* mid   = (unsigned short*)alloc(4096ull * 4096 * 2);
  float*          pbuf  = (float*)alloc(4ull * SZ_ACT * 4);                // split-K partials
  float*          qkvbias = (float*)alloc(3ull * 3072 * 4);
  float*          kvbias  = (float*)alloc(3ull * 2048 * 4);

  cvt_kernel<<<2048, 256, 0, stream>>>(wo, Wob, 1572864);
  cvt_kernel<<<2048, 256, 0, stream>>>(w1, W1b, 3145728);
  cvt_kernel<<<2048, 256, 0, stream>>>(w2, W2b, 3145728);
  cvt_kernel<<<2048, 256, 0, stream>>>(enc, encb, 1048576);
  pack_w<<<dim3(1024, 3, 3), 256, 0, stream>>>(wq, wk, wv, 0, qkvw, 3);
  pack_w<<<dim3(1024, 2, 3), 256, 0, stream>>>(wk, wv, wv, 1, kvw, 2);
  pack_w<<<dim3(1024, 1, 3), 256, 0, stream>>>(wq, wq, wq, 1, wqxb, 1);
  pack_bias<<<dim3(3, 3), 256, 0, stream>>>(bq, bk, bv, 0, qkvbias, 3);
  pack_bias<<<dim3(2, 3), 256, 0, stream>>>(bk, bv, bv, 1, kvbias, 2);
  embed_kernel<<<4096, 256, 0, stream>>>(dec, emb, pe, x);

  // merged cross-attn K/V for all 3 layers: [4096][6144]
  gemm8p<0><<<16 * 24, 512, 0, stream>>>(encb, kvw, kvbias, 6144, kvb);

  const dim3 gAttn(4, 16, 8);
  const dim3 gVt(8, 16, 8);

  for (int l = 0; l < 3; ++l) {
    const float* g0 = lng + (l * 3 + 0) * 1024; const float* e0 = lnb + (l * 3 + 0) * 1024;
    const float* g1 = lng + (l * 3 + 1) * 1024; const float* e1 = lnb + (l * 3 + 1) * 1024;
    const float* g2 = lng + (l * 3 + 2) * 1024; const float* e2 = lnb + (l * 3 + 2) * 1024;

    // ---- self-attention sublayer ----
    ln_kernel<<<4096, 64, 0, stream>>>(x, g0, e0, hb);
    gemm8p<0><<<16 * 12, 512, 0, stream>>>(hb, qkvw + (size_t)l * 3 * 1048576,
        qkvbias + l * 3072, 3072, qkvb);
    vt_kernel<<<gVt, 256, 0, stream>>>(qkvb + 2048, 3072, vtb);
    attn_kernel<true><<<gAttn, 256, 0, stream>>>(qkvb, 3072, qkvb + 1024, 3072, vtb, hb);
    gemm_bt<EPI_RES, 128, 64><<<32 * 16, 256, 0, stream>>>(hb, Wob + (size_t)(l * 2) * 1048576,
        bo + (l * 2) * 1024, 1024, 1024, 16, x, x, nullptr);

    // ---- cross-attention sublayer ----
    ln_kernel<<<4096, 64, 0, stream>>>(x, g1, e1, hb);
    gemm_bt<EPI_BF16, 128, 64><<<32 * 16, 256, 0, stream>>>(hb, wqxb + (size_t)l * 1048576,
        bq + (l * 2 + 1) * 1024, 1024, 1024, 16, qb, nullptr, nullptr);
    vt_kernel<<<gVt, 256, 0, stream>>>(kvb + l * 2048 + 1024, 6144, vtb);
    attn_kernel<false><<<gAttn, 256, 0, stream>>>(qb, 1024, kvb + l * 2048, 6144, vtb, hb);
    gemm_bt<EPI_RES2, 128, 64><<<32 * 16, 256, 0, stream>>>(hb, Wob + (size_t)(l * 2 + 1) * 1048576,
        bo + (l * 2 + 1) * 1024, 1024, 1024, 16, c, x, x);

    // ---- FFN sublayer (residual is c, per reference quirk) ----
    ln_kernel<<<4096, 64, 0, stream>>>(x, g2, e2, hb);
    gemm8p<1><<<16 * 16, 512, 0, stream>>>(hb, W1b + (size_t)l * 4194304,
        b1 + l * 4096, 4096, mid);
    // FFN2 via split-K=4 on the 8-phase engine -> f32 partials -> fused reduce
    gemm_sk8<<<256, 512, 0, stream>>>(mid, W2b + (size_t)l * 4194304, pbuf);
    float* xout = (l == 2) ? (float*)d_out : x;
    reduce4_kernel<<<2048, 256, 0, stream>>>(c, pbuf, b2 + l * 1024, xout);
  }
}